// Round 10
// baseline (625.127 us; speedup 1.0000x reference)
//
#include <hip/hip_runtime.h>
#include <math.h>

typedef short bf16x8_t __attribute__((ext_vector_type(8)));
typedef float f32x4_t  __attribute__((ext_vector_type(4)));

#define LOG2E 1.4426950408889634f

__device__ __forceinline__ float fast_rcp(float x) { return __builtin_amdgcn_rcpf(x); }
__device__ __forceinline__ float sigmoidf_(float x) {
  return fast_rcp(1.0f + __expf(-x));
}
// y = -log2e * x  (scaling pre-folded into weights/biases): sigmoid(x)
__device__ __forceinline__ float sigmoid2n_(float y) {
  return fast_rcp(1.0f + __builtin_amdgcn_exp2f(y));
}
// y = 2*log2e * x (pre-folded): tanh(x) = 1 - 2/(e^{2x}+1); inf-safe
__device__ __forceinline__ float tanh2n_(float y) {
  return fmaf(-2.0f, fast_rcp(__builtin_amdgcn_exp2f(y) + 1.0f), 1.0f);
}
__device__ __forceinline__ unsigned short f2bf(float f) {
  unsigned int u = __float_as_uint(f);
  unsigned int r = (u + 0x7fffu + ((u >> 16) & 1u)) >> 16;
  return (unsigned short)r;
}
__device__ __forceinline__ float bf2f(unsigned short u) {
  return __uint_as_float(((unsigned int)u) << 16);
}
// 2x f32 -> packed bf16 in one VALU op (gfx950; no builtin, inline asm per T12)
__device__ __forceinline__ unsigned int cvt_pk_bf16(float a, float b) {
  unsigned int d;
  asm("v_cvt_pk_bf16_f32 %0, %1, %2" : "=v"(d) : "v"(a), "v"(b));
  return d;
}

// ---------- dense 32-in/32-out linear: out = [relu?](X) @ W^T + b ----------
template<bool RELU_IN, bool OUT_BF16>
__global__ __launch_bounds__(256) void lin32_kernel(
    const float* __restrict__ X, const float* __restrict__ W,
    const float* __restrict__ b, void* __restrict__ outp, int N)
{
  __shared__ float sW[32][33];
  __shared__ float sb[32];
  __shared__ float sX[8][33];
  const int tid = threadIdx.x;
  for (int i = tid; i < 1024; i += 256) sW[i >> 5][i & 31] = W[i];
  if (tid < 32) sb[tid] = b[tid];
  const int n0 = blockIdx.x * 8;
  {
    float v = X[(size_t)n0 * 32 + tid];
    if (RELU_IN) v = fmaxf(v, 0.0f);
    sX[tid >> 5][tid & 31] = v;
  }
  __syncthreads();
  const int ln = tid >> 5, f = tid & 31;
  float acc = sb[f];
  #pragma unroll
  for (int j = 0; j < 32; j++) acc += sX[ln][j] * sW[f][j];
  if (OUT_BF16) ((unsigned short*)outp)[(size_t)n0 * 32 + tid] = f2bf(acc);
  else          ((float*)outp)[(size_t)n0 * 32 + tid] = acc;
}

// ---------- fallback SpMM (atomics, fp32) ----------
__global__ __launch_bounds__(256) void spmm_kernel(
    const int* __restrict__ erow, const int* __restrict__ ecol,
    const float* __restrict__ eval, const float* __restrict__ X,
    float* __restrict__ out, int E)
{
  const long gid = (long)blockIdx.x * 256 + threadIdx.x;
  const int e = (int)(gid >> 3);
  const int q = (int)(gid & 7);
  if (e >= E) return;
  const int r = erow[e], c = ecol[e];
  const float v = eval[e];
  const float4 x = *(const float4*)(X + (size_t)c * 32 + q * 4);
  float* o = out + (size_t)r * 32 + q * 4;
  atomicAdd(o + 0, v * x.x);
  atomicAdd(o + 1, v * x.y);
  atomicAdd(o + 2, v * x.z);
  atomicAdd(o + 3, v * x.w);
}

// ---------- 128-row bucket multisplit (tier A CSR build, stage 1) ----------
#define BROWS 128
#define BSHIFT 7
#define EPB 8192            // edges per binning block
#define MAXBUCKETS 1024

// lin32-g1 and hist_bin merged (independent subgraphs, one launch)
__global__ __launch_bounds__(256) void lin_hist_k(
    const float* __restrict__ X, const float* __restrict__ W,
    const float* __restrict__ b, unsigned short* __restrict__ outp,
    int N, int linBlocks,
    const int* __restrict__ erow, int* __restrict__ blockHist,
    int E, int nBuckets)
{
  __shared__ float sW[32][33];
  __shared__ float sb[32];
  __shared__ float sX[8][33];
  __shared__ int h[MAXBUCKETS];
  const int tid = threadIdx.x;
  if ((int)blockIdx.x < linBlocks) {
    for (int i = tid; i < 1024; i += 256) sW[i >> 5][i & 31] = W[i];
    if (tid < 32) sb[tid] = b[tid];
    const int n0 = blockIdx.x * 8;
    sX[tid >> 5][tid & 31] = X[(size_t)n0 * 32 + tid];
    __syncthreads();
    const int ln = tid >> 5, f = tid & 31;
    float acc = sb[f];
    #pragma unroll
    for (int j = 0; j < 32; j++) acc += sX[ln][j] * sW[f][j];
    outp[(size_t)n0 * 32 + tid] = f2bf(acc);
  } else {
    const int bid = blockIdx.x - linBlocks;
    for (int i = tid; i < nBuckets; i += 256) h[i] = 0;
    __syncthreads();
    const int e0 = bid * EPB;
    const int cnt = min(E - e0, EPB);
    for (int i = tid; i < cnt; i += 256)
      atomicAdd(&h[erow[e0 + i] >> BSHIFT], 1);
    __syncthreads();
    int* o = blockHist + (size_t)bid * nBuckets;
    for (int i = tid; i < nBuckets; i += 256) o[i] = h[i];
  }
}

// colscan_k: one block per bucket column; parallel replacement for the old
// single-block serial scan (was ~94us on one CU).
__global__ __launch_bounds__(128) void colscan_k(
    int* __restrict__ blockHist, int* __restrict__ bucketTotal,
    int nb, int nBuckets)
{
  __shared__ int s[128];
  const int b = blockIdx.x;          // bucket column
  const int t = threadIdx.x;
  const int k = (nb + 127) >> 7;     // segment length per thread
  const int i0 = t * k, i1 = min(nb, i0 + k);
  int p = 0;
  for (int i = i0; i < i1; i++) p += blockHist[(size_t)i * nBuckets + b];
  s[t] = p;
  __syncthreads();
  #pragma unroll
  for (int off = 1; off < 128; off <<= 1) {
    int u = (t >= off) ? s[t - off] : 0;
    __syncthreads(); s[t] += u; __syncthreads();
  }
  int run = s[t] - p;                // exclusive prefix for this segment
  if (t == 127) bucketTotal[b] = s[127];
  for (int i = i0; i < i1; i++) {
    int* q = &blockHist[(size_t)i * nBuckets + b];
    int v = *q;
    *q = run;
    run += v;
  }
}

// one block: exclusive scan of bucket totals -> bucketStart[0..nBuckets]
__global__ __launch_bounds__(1024) void bucketstart_k(
    const int* __restrict__ bucketTotal, int* __restrict__ bucketStart,
    int nBuckets)
{
  __shared__ int s[1024];
  const int b = threadIdx.x;
  int v = (b < nBuckets) ? bucketTotal[b] : 0;
  s[b] = v;
  __syncthreads();
  for (int off = 1; off < 1024; off <<= 1) {
    int u = (b >= off) ? s[b - off] : 0;
    __syncthreads(); s[b] += u; __syncthreads();
  }
  if (b < nBuckets) bucketStart[b] = s[b] - v;
  if (b == nBuckets - 1) bucketStart[nBuckets] = s[b];
}

// ---------- LDS-staged multisplit scatter ----------
// record = ((rowLocal(7b) << 17) | col(17b), val_f32) : 8B
__global__ __launch_bounds__(256) void scatter_stage_k(
    const int* __restrict__ erow, const int* __restrict__ ecol,
    const float* __restrict__ evl, const int* __restrict__ blockOfs,
    const int* __restrict__ bucketStart, int2* __restrict__ binned,
    int E, int nBuckets)
{
  __shared__ int2 rec[EPB];          // 64KB
  __shared__ int  dstv[EPB];         // 32KB  (global base for record's bucket)
  __shared__ int  cur[MAXBUCKETS];   // 4KB
  __shared__ int  gb[MAXBUCKETS];    // 4KB
  __shared__ int  part[256];         // 1KB
  const int tid = threadIdx.x;
  const int e0 = blockIdx.x * EPB;
  const int cntE = min(E - e0, EPB);
  const int* ofs = blockOfs + (size_t)blockIdx.x * nBuckets;

  for (int i = tid; i < nBuckets; i += 256) cur[i] = 0;
  __syncthreads();
  for (int i = tid; i < cntE; i += 256)
    atomicAdd(&cur[erow[e0 + i] >> BSHIFT], 1);
  __syncthreads();

  const int k = (nBuckets + 255) >> 8;
  const int i0 = tid * k, i1 = min(i0 + k, nBuckets);
  int s = 0;
  for (int i = i0; i < i1; i++) s += cur[i];
  part[tid] = s;
  __syncthreads();
  for (int off = 1; off < 256; off <<= 1) {
    int u = (tid >= off) ? part[tid - off] : 0;
    __syncthreads(); part[tid] += u; __syncthreads();
  }
  int run = part[tid] - s;
  for (int i = i0; i < i1; i++) {
    int hv = cur[i];
    gb[i] = bucketStart[i] + ofs[i] - run;  // final = gb[b] + localPos
    cur[i] = run;
    run += hv;
  }
  __syncthreads();

  for (int i = tid; i < cntE; i += 256) {
    int r = erow[e0 + i];
    int c = ecol[e0 + i];
    float v = evl[e0 + i];
    int b = r >> BSHIFT;
    int p = atomicAdd(&cur[b], 1);
    rec[p]  = make_int2(((r & (BROWS - 1)) << 17) | c, __float_as_int(v));
    dstv[p] = gb[b];
  }
  __syncthreads();

  for (int i = tid; i < cntE; i += 256)
    binned[dstv[i] + i] = rec[i];
}

// ---------- per-bucket counting sort -> exact CSR (tier A, stage 2) ----------
__global__ __launch_bounds__(512) void bucket_sort_k(
    const int* __restrict__ bucketStart, const int2* __restrict__ binned,
    int2* __restrict__ pairs, int* __restrict__ startv, int* __restrict__ cnt,
    int N)
{
  __shared__ int h[BROWS], sc[BROWS], cur[BROWS];
  const int tid = threadIdx.x;
  const int bkt = blockIdx.x;
  const int s = bucketStart[bkt], e = bucketStart[bkt + 1];
  if (tid < BROWS) h[tid] = 0;
  __syncthreads();
  for (int i = s + tid; i < e; i += 512)
    atomicAdd(&h[((unsigned)binned[i].x) >> 17], 1);
  __syncthreads();
  if (tid < BROWS) sc[tid] = h[tid];
  __syncthreads();
  #pragma unroll
  for (int off = 1; off < BROWS; off <<= 1) {
    int u = (tid < BROWS && tid >= off) ? sc[tid - off] : 0;
    __syncthreads();
    if (tid < BROWS) sc[tid] += u;
    __syncthreads();
  }
  if (tid < BROWS) {
    int start = s + sc[tid] - h[tid];
    cur[tid] = start;
    int row = (bkt << BSHIFT) + tid;
    if (row < N) { startv[row] = start; cnt[row] = h[tid]; }
  }
  __syncthreads();
  for (int i = s + tid; i < e; i += 512) {
    int2 r = binned[i];
    int p = atomicAdd(&cur[((unsigned)r.x) >> 17], 1);
    pairs[p] = make_int2(r.x & 0x1ffff, r.y);
  }
}

// ---------- tier B CSR build (round-0 baseline, exact but random scatter) ----
__global__ __launch_bounds__(256) void hist_k(const int* __restrict__ erow, int* cnt, int E) {
  int e = blockIdx.x * 256 + threadIdx.x;
  if (e < E) atomicAdd(&cnt[erow[e]], 1);
}

__global__ __launch_bounds__(256) void scan1_k(const int* __restrict__ cnt, int* startv, int* bsum, int N) {
  __shared__ int s[256];
  int t = threadIdx.x, i = blockIdx.x * 256 + t;
  int v = (i < N) ? cnt[i] : 0;
  s[t] = v; __syncthreads();
  for (int off = 1; off < 256; off <<= 1) {
    int u = (t >= off) ? s[t - off] : 0;
    __syncthreads(); s[t] += u; __syncthreads();
  }
  if (i < N) startv[i] = s[t] - v;
  if (t == 255) bsum[blockIdx.x] = s[255];
}

__global__ __launch_bounds__(512) void scan2_k(const int* __restrict__ bsum, int* bsumx, int nb) {
  __shared__ int s[512];
  int t = threadIdx.x;
  int v = (t < nb) ? bsum[t] : 0;
  s[t] = v; __syncthreads();
  for (int off = 1; off < 512; off <<= 1) {
    int u = (t >= off) ? s[t - off] : 0;
    __syncthreads(); s[t] += u; __syncthreads();
  }
  if (t < nb) bsumx[t] = s[t] - v;
}

__global__ __launch_bounds__(256) void scan3_k(int* startv, const int* __restrict__ bsumx, int* cursor, int N) {
  int i = blockIdx.x * 256 + threadIdx.x;
  if (i < N) {
    int v = startv[i] + bsumx[i >> 8];
    startv[i] = v;
    cursor[i] = v;
  }
}

__global__ __launch_bounds__(256) void scatter_k(
    const int* __restrict__ erow, const int* __restrict__ ecol,
    const float* __restrict__ evl, int* cursor, int2* __restrict__ pairs, int E)
{
  int e = blockIdx.x * 256 + threadIdx.x;
  if (e < E) {
    int r = erow[e];
    int p = atomicAdd(&cursor[r], 1);
    pairs[p] = make_int2(ecol[e], __float_as_int(evl[e]));
  }
}

// ---------- CSR SpMM: one wave per row; lanes 0-31 = features ----------
// Each half-wave owns a contiguous half of the row's edges; 8 pairs + 8
// X-gathers in flight per stream. FUSE_LIN: apply relu + 32x32 linear (W,b)
// in the epilogue and write bf16. NOTE: FUSE_LIN out MUST NOT alias X —
// round-9's in-place launch (X=out=buf0h) raced gather reads vs epilogue
// writes (absmax 1.95e-2 fail). Fixed: out -> separate buffer.
template<bool FUSE_LIN>
__global__ __launch_bounds__(256) void spmm_csr_bf16_k(
    const int* __restrict__ startv, const int* __restrict__ cnt,
    const int2* __restrict__ pairs, const unsigned short* __restrict__ X,
    void* __restrict__ outp, const float* __restrict__ W,
    const float* __restrict__ b, int N)
{
  __shared__ float sW[32][33];
  __shared__ float sb[32];
  __shared__ float sAcc[4][32];
  const int tid = threadIdx.x;
  if (FUSE_LIN) {
    for (int i = tid; i < 1024; i += 256) sW[i >> 5][i & 31] = W[i];
    if (tid < 32) sb[tid] = b[tid];
    __syncthreads();
  }
  int row = blockIdx.x * 4 + (tid >> 6);
  if (row >= N) return;
  int lane = tid & 63;
  int f = lane & 31, hh = lane >> 5;
  int start = startv[row];
  int len = cnt[row];
  int half = len >> 1;
  int base = start + (hh ? half : 0);
  int n = hh ? (len - half) : half;
  float acc = 0.0f;
  int i = 0;
  for (; i + 7 < n; i += 8) {
    int2 p0 = pairs[base + i + 0];
    int2 p1 = pairs[base + i + 1];
    int2 p2 = pairs[base + i + 2];
    int2 p3 = pairs[base + i + 3];
    int2 p4 = pairs[base + i + 4];
    int2 p5 = pairs[base + i + 5];
    int2 p6 = pairs[base + i + 6];
    int2 p7 = pairs[base + i + 7];
    float x0 = bf2f(X[(size_t)p0.x * 32 + f]);
    float x1 = bf2f(X[(size_t)p1.x * 32 + f]);
    float x2 = bf2f(X[(size_t)p2.x * 32 + f]);
    float x3 = bf2f(X[(size_t)p3.x * 32 + f]);
    float x4 = bf2f(X[(size_t)p4.x * 32 + f]);
    float x5 = bf2f(X[(size_t)p5.x * 32 + f]);
    float x6 = bf2f(X[(size_t)p6.x * 32 + f]);
    float x7 = bf2f(X[(size_t)p7.x * 32 + f]);
    acc = fmaf(__int_as_float(p0.y), x0, acc);
    acc = fmaf(__int_as_float(p1.y), x1, acc);
    acc = fmaf(__int_as_float(p2.y), x2, acc);
    acc = fmaf(__int_as_float(p3.y), x3, acc);
    acc = fmaf(__int_as_float(p4.y), x4, acc);
    acc = fmaf(__int_as_float(p5.y), x5, acc);
    acc = fmaf(__int_as_float(p6.y), x6, acc);
    acc = fmaf(__int_as_float(p7.y), x7, acc);
  }
  for (; i + 3 < n; i += 4) {
    int2 p0 = pairs[base + i + 0];
    int2 p1 = pairs[base + i + 1];
    int2 p2 = pairs[base + i + 2];
    int2 p3 = pairs[base + i + 3];
    float x0 = bf2f(X[(size_t)p0.x * 32 + f]);
    float x1 = bf2f(X[(size_t)p1.x * 32 + f]);
    float x2 = bf2f(X[(size_t)p2.x * 32 + f]);
    float x3 = bf2f(X[(size_t)p3.x * 32 + f]);
    acc = fmaf(__int_as_float(p0.y), x0, acc);
    acc = fmaf(__int_as_float(p1.y), x1, acc);
    acc = fmaf(__int_as_float(p2.y), x2, acc);
    acc = fmaf(__int_as_float(p3.y), x3, acc);
  }
  for (; i < n; i++) {
    int2 p = pairs[base + i];
    acc = fmaf(__int_as_float(p.y), bf2f(X[(size_t)p.x * 32 + f]), acc);
  }
  acc += __shfl_down(acc, 32);
  if (!FUSE_LIN) {
    if (hh == 0) ((float*)outp)[(size_t)row * 32 + f] = acc;
  } else {
    // fused relu + 32x32 linear: per-wave LDS stage (wave-local RAW, no barrier)
    const int w = tid >> 6;
    if (hh == 0) sAcc[w][f] = fmaxf(acc, 0.0f);
    float part = 0.0f;
    #pragma unroll
    for (int j0 = 0; j0 < 16; j0++) {
      int j = hh * 16 + j0;
      part = fmaf(sAcc[w][j], sW[f][j], part);
    }
    part += __shfl_down(part, 32);
    if (hh == 0)
      ((unsigned short*)outp)[(size_t)row * 32 + f] = f2bf(sb[f] + part);
  }
}

// ---------- fused MFMA GRU + head, 32 nodes / block ----------
// exp2 pre-scaling: v_exp_f32 IS exp2 — r/z rows+biases scaled by -log2e
// (sigmoid = rcp(1+exp2(y))), n-path by 2*log2e (tanh = fma(-2,rcp(exp2+1),1)),
// h2 path by -log2e. VGPR 84, launch_bounds (256,2): (256,4) spills.
#define NB 32

__global__ __launch_bounds__(256, 2) void gru_head_mfma(
    const float* __restrict__ acc2,   // (N,32) pre-relu graph output
    const float* __restrict__ xdyn,   // (T,N,8)
    const float* __restrict__ Wih,    // (192,40)
    const float* __restrict__ Whh,    // (192,64)
    const float* __restrict__ bih, const float* __restrict__ bhh,
    const float* __restrict__ h1W,    // (64,64)
    const float* __restrict__ h1b, const float* __restrict__ h2W,
    const float* __restrict__ h2b,
    float* __restrict__ out, int N, int T)
{
  __shared__ __align__(16) unsigned short z[2][NB][104];  // [buf][n][k] bf16
  __shared__ float s_red[2][NB][5];                       // double-buffered head partials

  const int tid  = threadIdx.x;
  const int w    = tid >> 6;       // wave 0..3
  const int lane = tid & 63;
  const int ml   = lane & 15;      // A-row / B-col within tile
  const int q    = lane >> 4;      // quad
  const int n0   = blockIdx.x * NB;

  const float SR = -LOG2E;         // sigmoid arg scale
  const float SN = 2.0f * LOG2E;   // tanh arg scale

  // ---- A fragments (weights), built once; scales folded in ----
  bf16x8_t A_r[3], A_z[3], A_in, A_hn[2];
  {
    const int j = 16 * w + ml;
    #pragma unroll
    for (int s = 0; s < 3; s++) {
      union { bf16x8_t v; unsigned short u[8]; } tr, tz;
      #pragma unroll
      for (int jj = 0; jj < 8; jj++) {
        int k = s * 32 + q * 8 + jj;
        float vr = (k < 64) ? Whh[j * 64 + k]        : (k < 72 ? Wih[j * 40 + 32 + (k - 64)] : 0.0f);
        float vz = (k < 64) ? Whh[(64 + j) * 64 + k] : (k < 72 ? Wih[(64 + j) * 40 + 32 + (k - 64)] : 0.0f);
        tr.u[jj] = f2bf(SR * vr);
        tz.u[jj] = f2bf(SR * vz);
      }
      A_r[s] = tr.v; A_z[s] = tz.v;
    }
    union { bf16x8_t v; unsigned short u[8]; } ti;
    #pragma unroll
    for (int jj = 0; jj < 8; jj++) {
      int kk = q * 8 + jj;
      ti.u[jj] = f2bf((kk < 8) ? SN * Wih[(128 + j) * 40 + 32 + kk] : 0.0f);
    }
    A_in = ti.v;
    #pragma unroll
    for (int s = 0; s < 2; s++) {
      union { bf16x8_t v; unsigned short u[8]; } th;
      #pragma unroll
      for (int jj = 0; jj < 8; jj++)
        th.u[jj] = f2bf(SN * Whh[(128 + j) * 64 + s * 32 + q * 8 + jj]);
      A_hn[s] = th.v;
    }
  }
  bf16x8_t Ah[2];   // head h1W (64x64) UNSCALED (relu needs true values)
  #pragma unroll
  for (int s = 0; s < 2; s++) {
    union { bf16x8_t v; unsigned short u[8]; } tmp;
    #pragma unroll
    for (int jj = 0; jj < 8; jj++)
      tmp.u[jj] = f2bf(h1W[(16 * w + ml) * 64 + s * 32 + q * 8 + jj]);
    Ah[s] = tmp.v;
  }

  // per-reg persistent constants (j = 16w+4q+reg); h2 path pre-scaled by SR
  f32x4_t bhhn4, h1b4;
  float h2w_r[4];
  #pragma unroll
  for (int reg = 0; reg < 4; reg++) {
    int j = 16 * w + 4 * q + reg;
    bhhn4[reg] = SN * bhh[128 + j];
    h1b4[reg]  = h1b[j];
    h2w_r[reg] = SR * h2W[j];
  }
  const float h2b0 = SR * h2b[0];

  // ---- stage hg = relu(acc2) bf16 into z[0] cols 0..32 ----
  {
    int nd = tid >> 3, f0 = (tid & 7) * 4;
    float4 v = *(const float4*)(acc2 + (size_t)(n0 + nd) * 32 + f0);
    uint2 pk;
    pk.x = cvt_pk_bf16(fmaxf(v.x, 0.0f), fmaxf(v.y, 0.0f));
    pk.y = cvt_pk_bf16(fmaxf(v.z, 0.0f), fmaxf(v.w, 0.0f));
    *(uint2*)&z[0][nd][f0] = pk;
  }
  __syncthreads();

  // gis = W_is @ hg^T (K=32), scales + biases folded in
  f32x4_t gis[3][2];
  {
    bf16x8_t Ag[3];
    #pragma unroll
    for (int g = 0; g < 3; g++) {
      const float sg = (g < 2) ? SR : SN;
      union { bf16x8_t v; unsigned short u[8]; } tmp;
      #pragma unroll
      for (int jj = 0; jj < 8; jj++)
        tmp.u[jj] = f2bf(sg * Wih[(g * 64 + 16 * w + ml) * 40 + q * 8 + jj]);
      Ag[g] = tmp.v;
    }
    bf16x8_t Bg[2];
    #pragma unroll
    for (int nt = 0; nt < 2; nt++)
      Bg[nt] = *(const bf16x8_t*)&z[0][nt * 16 + ml][q * 8];
    f32x4_t zero = {0.0f, 0.0f, 0.0f, 0.0f};
    #pragma unroll
    for (int g = 0; g < 3; g++)
      #pragma unroll
      for (int nt = 0; nt < 2; nt++)
        gis[g][nt] = __builtin_amdgcn_mfma_f32_16x16x32_bf16(Ag[g], Bg[nt], zero, 0, 0, 0);
  }
  __syncthreads();   // gis B-reads complete before zeroing

  for (int i = tid; i < 2 * NB * 104 / 2; i += 256) ((unsigned int*)z)[i] = 0;
  #pragma unroll
  for (int reg = 0; reg < 4; reg++) {
    int j = 16 * w + 4 * q + reg;
    float br = SR * (bih[j] + bhh[j]);
    float bz = SR * (bih[64 + j] + bhh[64 + j]);
    float bn = SN * bih[128 + j];
    #pragma unroll
    for (int nt = 0; nt < 2; nt++) {
      gis[0][nt][reg] += br;
      gis[1][nt][reg] += bz;
      gis[2][nt][reg] += bn;
    }
  }
  __syncthreads();

  float hreg[2][4] = {{0, 0, 0, 0}, {0, 0, 0, 0}};

  // prefetch xd(0)
  float4 xv = make_float4(0.f, 0.f, 0.f, 0.f);
  if (tid < 64) xv = *(const float4*)(xdyn + (size_t)n0 * 8 + tid * 4);

  for (int t = 0; t < T; t++) {
    const int b = t & 1;
    // stage xd(t) into z[b] cols 64..72; prefetch xd(t+1)
    if (tid < 64) {
      uint2 pk;
      pk.x = cvt_pk_bf16(xv.x, xv.y);
      pk.y = cvt_pk_bf16(xv.z, xv.w);
      *(uint2*)&z[b][tid >> 1][64 + (tid & 1) * 4] = pk;
      if (t + 1 < T)
        xv = *(const float4*)(xdyn + ((size_t)(t + 1) * N + n0) * 8 + tid * 4);
    }
    __syncthreads();   // S1 (the ONLY barrier per step)

    // reduce + output for step t-2
    if (t >= 2 && tid < 32) {
      float s = s_red[1 - b][tid][0] + s_red[1 - b][tid][1] +
                s_red[1 - b][tid][2] + s_red[1 - b][tid][3];
      out[(size_t)(t - 2) * N + n0 + tid] = sigmoid2n_(s + h2b0);
    }

    #pragma unroll
    for (int nt = 0; nt < 2; nt++) {
      bf16x8_t B0 = *(const bf16x8_t*)&z[b][nt * 16 + ml][q * 8];
      bf16x8_t B1 = *(const bf16x8_t*)&z[b][nt * 16 + ml][32 + q * 8];
      bf16x8_t B2 = *(const bf16x8_t*)&z[b][nt * 16 + ml][64 + q * 8];

      // main GEMM (gates for step t); gis/bhh_n ride in as C-in
      f32x4_t ar  = gis[0][nt];
      f32x4_t az  = gis[1][nt];
      f32x4_t ain = gis[2][nt];
      f32x4_t ahn = bhhn4;
      ar  = __builtin_amdgcn_mfma_f32_16x16x32_bf16(A_r[0], B0, ar, 0, 0, 0);
      az  = __builtin_amdgcn_mfma_f32_16x16x32_bf16(A_z[0], B0, az, 0, 0, 0);
      ahn = __builtin_amdgcn_mfma_f32_16x16x32_bf16(A_hn[0], B0, ahn, 0, 0, 0);
      ar  = __builtin_amdgcn_mfma_f32_16x16x32_bf16(A_r[1], B1, ar, 0, 0, 0);
      az  = __builtin_amdgcn_mfma_f32_16x16x32_bf16(A_z[1], B1, az, 0, 0, 0);
      ahn = __builtin_amdgcn_mfma_f32_16x16x32_bf16(A_hn[1], B1, ahn, 0, 0, 0);
      ar  = __builtin_amdgcn_mfma_f32_16x16x32_bf16(A_r[2], B2, ar, 0, 0, 0);
      az  = __builtin_amdgcn_mfma_f32_16x16x32_bf16(A_z[2], B2, az, 0, 0, 0);
      ain = __builtin_amdgcn_mfma_f32_16x16x32_bf16(A_in,  B2, ain, 0, 0, 0);

      // head GEMM for step t-1: B0/B1 ARE h_{t-1}; h1b rides in as C-in
      if (t >= 1) {
        f32x4_t ha = h1b4;
        ha = __builtin_amdgcn_mfma_f32_16x16x32_bf16(Ah[0], B0, ha, 0, 0, 0);
        ha = __builtin_amdgcn_mfma_f32_16x16x32_bf16(Ah[1], B1, ha, 0, 0, 0);
        float p = 0.0f;
        #pragma unroll
        for (int reg = 0; reg < 4; reg++)
          p += h2w_r[reg] * fmaxf(ha[reg], 0.0f);
        p += __shfl_xor(p, 16, 64);
        p += __shfl_xor(p, 32, 64);
        if (q == 0) s_red[b][nt * 16 + ml][w] = p;
      }

      // epilogue: gates (exp2-prescaled) + state update; h_t -> other buffer
      float hv[4];
      #pragma unroll
      for (int reg = 0; reg < 4; reg++) {
        float r  = sigmoid2n_(ar[reg]);
        float zg = sigmoid2n_(az[reg]);
        float nn = tanh2n_(fmaf(r, ahn[reg], ain[reg]));
        float h  = fmaf(zg, hreg[nt][reg] - nn, nn);
        hreg[nt][reg] = h;
        hv[reg] = h;
      }
      uint2 pk;
      pk.x = cvt_pk_bf16(hv[0], hv[1]);
      pk.y = cvt_pk_bf16(hv[2], hv[3]);
      *(uint2*)&z[1 - b][nt * 16 + ml][16 * w + 4 * q] = pk;
    }
  }

  // ---- drain: head(T-1), out(T-2), out(T-1) ----
  const int bl = (T - 1) & 1;
  __syncthreads();

  if (tid < 32) {
    float s = s_red[bl][tid][0] + s_red[bl][tid][1] +
              s_red[bl][tid][2] + s_red[bl][tid][3];
    out[(size_t)(T - 2) * N + n0 + tid] = sigmoid2n_(s + h2b0);
  }
  #pragma unroll
  for (int nt = 0; nt < 2; nt++) {
    bf16x8_t B0 = *(const bf16x8_t*)&z[1 - bl][nt * 16 + ml][q * 8];
    bf16x8_t B1 = *(const bf16x8_t*)&z[1 - bl][nt * 16 + ml][32 + q * 8];
    f32x4_t ha = h1b4;
    ha = __builtin_amdgcn_mfma_f32_16x16x32_bf16(Ah[0], B0, ha, 0, 0, 0);
    ha = __builtin_amdgcn_mfma_f32_16x16x32_bf16(Ah[1], B1, ha, 0, 0, 0);
    float p = 0.0f;
    #pragma unroll
    for (int reg = 0; reg < 4; reg++)
      p += h2w_r[reg] * fmaxf(ha[reg], 0.0f);
    p += __shfl_xor(p, 16, 64);
    p += __shfl_xor(p, 32, 64);
    if (q == 0) s_red[1 - bl][nt * 16 + ml][w] = p;
  }
  __syncthreads();
  if (tid < 32) {
    float s = s_red[1 - bl][tid][0] + s_red[1 - bl][tid][1] +
              s_red[1 - bl][tid][2] + s_red[1 - bl][tid][3];
    out[(size_t)(T - 1) * N + n0 + tid] = sigmoid2n_(s + h2b0);
  }
}

extern "C" void kernel_launch(void* const* d_in, const int* in_sizes, int n_in,
                              void* d_out, int out_size, void* d_ws, size_t ws_size,
                              hipStream_t stream) {
  const float* Xs   = (const float*)d_in[0];
  const float* Xd   = (const float*)d_in[1];
  const int*   erow = (const int*)d_in[2];
  const int*   ecol = (const int*)d_in[3];
  const float* evl  = (const float*)d_in[4];
  const float* g1W  = (const float*)d_in[5];
  const float* g1b  = (const float*)d_in[6];
  const float* g2W  = (const float*)d_in[7];
  const float* g2b  = (const float*)d_in[8];
  const float* Wih  = (const float*)d_in[9];
  const float* Whh  = (const float*)d_in[10];
  const float* bih  = (const float*)d_in[11];
  const float* bhh  = (const float*)d_in[12];
  const float* h1W  = (const float*)d_in[13];
  const float* h1b  = (const float*)d_in[14];
  const float* h2W  = (const float*)d_in[15];
  const float* h2b  = (const float*)d_in[16];

  const int N = in_sizes[0] / 32;
  const int E = in_sizes[2];
  const int T = in_sizes[1] / (N * 8);

  float* out  = (float*)d_out;
  char*  base = (char*)d_ws;
  float* buf0 = (float*)base;                     // N*32 f32 (also aliased as bf16)
  float* buf1 = buf0 + (size_t)N * 32;            // N*32 f32 (also aliased as bf16)
  int*   cnt    = (int*)(buf1 + (size_t)N * 32);  // N
  int*   startv = cnt + N;                        // N
  int*   cursor = startv + N;                     // N (tier B only)
  int*   bsum   = cursor + N;                     // 512 (tier B only)
  int*   bsumx  = bsum + 512;                     // 512 (tier B only)
  unsigned short* buf0h = (unsigned short*)buf0;  // bf16 view of buf0
  unsigned short* buf1h = (unsigned short*)buf1;  // bf16 view of buf1

  const int nBuckets = (N + BROWS - 1) >> BSHIFT;
  const int nbBin    = (E + EPB - 1) / EPB;

  int* bucketStart = bsumx + 512;                       // nBuckets+1
  int* bucketTotal = bucketStart + nBuckets + 1;        // nBuckets
  int* blockHist   = bucketTotal + nBuckets;            // nbBin*nBuckets
  char* pp = (char*)(blockHist + (size_t)nbBin * nBuckets);
  pp = (char*)(((uintptr_t)pp + 15) & ~(uintptr_t)15);
  int2* pairs  = (int2*)pp;                             // E (both tiers)
  int2* binned = pairs + E;                             // E (tier A only)

  const size_t neededA = (size_t)((char*)(binned + E) - base);
  const size_t neededB = (size_t)((char*)(pairs + E) - base);

  const int linBlocks = (N + 7) / 8;
  const int eBlocks   = (E + 255) / 256;
  const int nb1       = (N + 255) / 256;

  const bool tierA = (ws_size >= neededA) && (nBuckets <= MAXBUCKETS) &&
                     (N <= (1 << 17));
  const bool tierB = !tierA && (ws_size >= neededB);

  if (tierA) {
    // lin32-g1 and hist_bin merged (independent subgraphs, one launch)
    lin_hist_k<<<linBlocks + nbBin, 256, 0, stream>>>(
        Xs, g1W, g1b, buf0h, N, linBlocks, erow, blockHist, E, nBuckets);

    colscan_k<<<nBuckets, 128, 0, stream>>>(blockHist, bucketTotal, nbBin, nBuckets);
    bucketstart_k<<<1, 1024, 0, stream>>>(bucketTotal, bucketStart, nBuckets);
    scatter_stage_k<<<nbBin, 256, 0, stream>>>(erow, ecol, evl, blockHist,
                                               bucketStart, binned, E, nBuckets);
    bucket_sort_k<<<nBuckets, 512, 0, stream>>>(bucketStart, binned, pairs,
                                                startv, cnt, N);

    // spmm1 fused relu+lin32-g2: read buf0h, write bf16 -> buf1h (NO alias)
    spmm_csr_bf16_k<true><<<(N + 3) / 4, 256, 0, stream>>>(
        startv, cnt, pairs, buf0h, buf1h, g2W, g2b, N);
    // spmm2: read buf1h, write f32 -> buf0
    spmm_csr_bf16_k<false><<<(N + 3) / 4, 256, 0, stream>>>(
        startv, cnt, pairs, buf1h, buf0, nullptr, nullptr, N);
  } else if (tierB) {
    // round-0 baseline CSR build (exact, random scatter)
    lin32_kernel<false, true><<<linBlocks, 256, 0, stream>>>(Xs, g1W, g1b, buf0h, N);

    hipMemsetAsync(cnt, 0, (size_t)N * sizeof(int), stream);
    hist_k<<<eBlocks, 256, 0, stream>>>(erow, cnt, E);
    scan1_k<<<nb1, 256, 0, stream>>>(cnt, startv, bsum, N);
    scan2_k<<<1, 512, 0, stream>>>(bsum, bsumx, nb1);
    scan3_k<<<nb1, 256, 0, stream>>>(startv, bsumx, cursor, N);
    scatter_k<<<eBlocks, 256, 0, stream>>>(erow, ecol, evl, cursor, pairs, E);

    spmm_csr_bf16_k<true><<<(N + 3) / 4, 256, 0, stream>>>(
        startv, cnt, pairs, buf0h, buf1h, g2W, g2b, N);
    spmm_csr_bf16_k<false><<<(N + 3) / 4, 256, 0, stream>>>(
        startv, cnt, pairs, buf1h, buf0, nullptr, nullptr, N);
  } else {
    // atomic fallback
    lin32_kernel<false, false><<<linBlocks, 256, 0, stream>>>(Xs, g1W, g1b, buf1, N);
    const int spmmBlocks = (int)(((long)E * 8 + 255) / 256);
    hipMemsetAsync(buf0, 0, (size_t)N * 32 * sizeof(float), stream);
    spmm_kernel<<<spmmBlocks, 256, 0, stream>>>(erow, ecol, evl, buf1, buf0, E);
    lin32_kernel<true, false><<<linBlocks, 256, 0, stream>>>(buf0, g2W, g2b, buf1, N);
    hipMemsetAsync(buf0, 0, (size_t)N * 32 * sizeof(float), stream);
    spmm_kernel<<<spmmBlocks, 256, 0, stream>>>(erow, ecol, evl, buf1, buf0, E);
  }

  // fused MFMA GRU + head (acc2 = buf0, f32)
  gru_head_mfma<<<N / NB, 256, 0, stream>>>(buf0, Xd, Wih, Whh, bih, bhh,
                                            h1W, h1b, h2W, h2b, out, N, T);
}

// Round 11
// 578.077 us; speedup vs baseline: 1.0814x; 1.0814x over previous
//
#include <hip/hip_runtime.h>
#include <math.h>

typedef short bf16x8_t __attribute__((ext_vector_type(8)));
typedef float f32x4_t  __attribute__((ext_vector_type(4)));

__device__ __forceinline__ float fast_rcp(float x) { return __builtin_amdgcn_rcpf(x); }
__device__ __forceinline__ float sigmoidf_(float x) {
  return fast_rcp(1.0f + __expf(-x));
}
__device__ __forceinline__ float tanhf_(float x) {
  // tanh(x) = 1 - 2/(e^{2x}+1); inf-safe without clamps (exp->inf => rcp->0 => 1)
  return fmaf(-2.0f, fast_rcp(__expf(2.0f * x) + 1.0f), 1.0f);
}
__device__ __forceinline__ unsigned short f2bf(float f) {
  unsigned int u = __float_as_uint(f);
  unsigned int r = (u + 0x7fffu + ((u >> 16) & 1u)) >> 16;
  return (unsigned short)r;
}
__device__ __forceinline__ float bf2f(unsigned short u) {
  return __uint_as_float(((unsigned int)u) << 16);
}
// 2x f32 -> packed bf16 in one VALU op (gfx950; no builtin, inline asm per T12)
__device__ __forceinline__ unsigned int cvt_pk_bf16(float a, float b) {
  unsigned int d;
  asm("v_cvt_pk_bf16_f32 %0, %1, %2" : "=v"(d) : "v"(a), "v"(b));
  return d;
}

// ---------- dense 32-in/32-out linear: out = [relu?](X) @ W^T + b ----------
template<bool RELU_IN, bool OUT_BF16>
__global__ __launch_bounds__(256) void lin32_kernel(
    const float* __restrict__ X, const float* __restrict__ W,
    const float* __restrict__ b, void* __restrict__ outp, int N)
{
  __shared__ float sW[32][33];
  __shared__ float sb[32];
  __shared__ float sX[8][33];
  const int tid = threadIdx.x;
  for (int i = tid; i < 1024; i += 256) sW[i >> 5][i & 31] = W[i];
  if (tid < 32) sb[tid] = b[tid];
  const int n0 = blockIdx.x * 8;
  {
    float v = X[(size_t)n0 * 32 + tid];
    if (RELU_IN) v = fmaxf(v, 0.0f);
    sX[tid >> 5][tid & 31] = v;
  }
  __syncthreads();
  const int ln = tid >> 5, f = tid & 31;
  float acc = sb[f];
  #pragma unroll
  for (int j = 0; j < 32; j++) acc += sX[ln][j] * sW[f][j];
  if (OUT_BF16) ((unsigned short*)outp)[(size_t)n0 * 32 + tid] = f2bf(acc);
  else          ((float*)outp)[(size_t)n0 * 32 + tid] = acc;
}

// ---------- fallback SpMM (atomics, fp32) ----------
__global__ __launch_bounds__(256) void spmm_kernel(
    const int* __restrict__ erow, const int* __restrict__ ecol,
    const float* __restrict__ eval, const float* __restrict__ X,
    float* __restrict__ out, int E)
{
  const long gid = (long)blockIdx.x * 256 + threadIdx.x;
  const int e = (int)(gid >> 3);
  const int q = (int)(gid & 7);
  if (e >= E) return;
  const int r = erow[e], c = ecol[e];
  const float v = eval[e];
  const float4 x = *(const float4*)(X + (size_t)c * 32 + q * 4);
  float* o = out + (size_t)r * 32 + q * 4;
  atomicAdd(o + 0, v * x.x);
  atomicAdd(o + 1, v * x.y);
  atomicAdd(o + 2, v * x.z);
  atomicAdd(o + 3, v * x.w);
}

// ---------- 128-row bucket multisplit (tier A CSR build, stage 1) ----------
#define BROWS 128
#define BSHIFT 7
// Round-11: EPB 8192->4096. scatter_stage LDS drops 105KB->57KB so 2
// blocks/CU (8 waves) instead of 1 (4 waves) — it's latency-bound (global
// loads + LDS atomics), occupancy is the lever.
#define EPB 4096            // edges per binning block
#define MAXBUCKETS 1024

// lin32-g1 and hist_bin merged (independent subgraphs, one launch)
__global__ __launch_bounds__(256) void lin_hist_k(
    const float* __restrict__ X, const float* __restrict__ W,
    const float* __restrict__ b, unsigned short* __restrict__ outp,
    int N, int linBlocks,
    const int* __restrict__ erow, int* __restrict__ blockHist,
    int E, int nBuckets)
{
  __shared__ float sW[32][33];
  __shared__ float sb[32];
  __shared__ float sX[8][33];
  __shared__ int h[MAXBUCKETS];
  const int tid = threadIdx.x;
  if ((int)blockIdx.x < linBlocks) {
    for (int i = tid; i < 1024; i += 256) sW[i >> 5][i & 31] = W[i];
    if (tid < 32) sb[tid] = b[tid];
    const int n0 = blockIdx.x * 8;
    sX[tid >> 5][tid & 31] = X[(size_t)n0 * 32 + tid];
    __syncthreads();
    const int ln = tid >> 5, f = tid & 31;
    float acc = sb[f];
    #pragma unroll
    for (int j = 0; j < 32; j++) acc += sX[ln][j] * sW[f][j];
    outp[(size_t)n0 * 32 + tid] = f2bf(acc);
  } else {
    const int bid = blockIdx.x - linBlocks;
    for (int i = tid; i < nBuckets; i += 256) h[i] = 0;
    __syncthreads();
    const int e0 = bid * EPB;
    const int cnt = min(E - e0, EPB);
    for (int i = tid; i < cnt; i += 256)
      atomicAdd(&h[erow[e0 + i] >> BSHIFT], 1);
    __syncthreads();
    int* o = blockHist + (size_t)bid * nBuckets;
    for (int i = tid; i < nBuckets; i += 256) o[i] = h[i];
  }
}

// colscan_k: one block per bucket column; parallel replacement for the old
// single-block serial scan (was ~94us on one CU).
__global__ __launch_bounds__(128) void colscan_k(
    int* __restrict__ blockHist, int* __restrict__ bucketTotal,
    int nb, int nBuckets)
{
  __shared__ int s[128];
  const int b = blockIdx.x;          // bucket column
  const int t = threadIdx.x;
  const int k = (nb + 127) >> 7;     // segment length per thread
  const int i0 = t * k, i1 = min(nb, i0 + k);
  int p = 0;
  for (int i = i0; i < i1; i++) p += blockHist[(size_t)i * nBuckets + b];
  s[t] = p;
  __syncthreads();
  #pragma unroll
  for (int off = 1; off < 128; off <<= 1) {
    int u = (t >= off) ? s[t - off] : 0;
    __syncthreads(); s[t] += u; __syncthreads();
  }
  int run = s[t] - p;                // exclusive prefix for this segment
  if (t == 127) bucketTotal[b] = s[127];
  for (int i = i0; i < i1; i++) {
    int* q = &blockHist[(size_t)i * nBuckets + b];
    int v = *q;
    *q = run;
    run += v;
  }
}

// one block: exclusive scan of bucket totals -> bucketStart[0..nBuckets]
__global__ __launch_bounds__(1024) void bucketstart_k(
    const int* __restrict__ bucketTotal, int* __restrict__ bucketStart,
    int nBuckets)
{
  __shared__ int s[1024];
  const int b = threadIdx.x;
  int v = (b < nBuckets) ? bucketTotal[b] : 0;
  s[b] = v;
  __syncthreads();
  for (int off = 1; off < 1024; off <<= 1) {
    int u = (b >= off) ? s[b - off] : 0;
    __syncthreads(); s[b] += u; __syncthreads();
  }
  if (b < nBuckets) bucketStart[b] = s[b] - v;
  if (b == nBuckets - 1) bucketStart[nBuckets] = s[b];
}

// ---------- LDS-staged multisplit scatter ----------
// record = ((rowLocal(7b) << 17) | col(17b), val_f32) : 8B
__global__ __launch_bounds__(256) void scatter_stage_k(
    const int* __restrict__ erow, const int* __restrict__ ecol,
    const float* __restrict__ evl, const int* __restrict__ blockOfs,
    const int* __restrict__ bucketStart, int2* __restrict__ binned,
    int E, int nBuckets)
{
  __shared__ int2 rec[EPB];          // 32KB
  __shared__ int  dstv[EPB];         // 16KB  (global base for record's bucket)
  __shared__ int  cur[MAXBUCKETS];   // 4KB
  __shared__ int  gb[MAXBUCKETS];    // 4KB
  __shared__ int  part[256];         // 1KB
  const int tid = threadIdx.x;
  const int e0 = blockIdx.x * EPB;
  const int cntE = min(E - e0, EPB);
  const int* ofs = blockOfs + (size_t)blockIdx.x * nBuckets;

  for (int i = tid; i < nBuckets; i += 256) cur[i] = 0;
  __syncthreads();
  for (int i = tid; i < cntE; i += 256)
    atomicAdd(&cur[erow[e0 + i] >> BSHIFT], 1);
  __syncthreads();

  const int k = (nBuckets + 255) >> 8;
  const int i0 = tid * k, i1 = min(i0 + k, nBuckets);
  int s = 0;
  for (int i = i0; i < i1; i++) s += cur[i];
  part[tid] = s;
  __syncthreads();
  for (int off = 1; off < 256; off <<= 1) {
    int u = (tid >= off) ? part[tid - off] : 0;
    __syncthreads(); part[tid] += u; __syncthreads();
  }
  int run = part[tid] - s;
  for (int i = i0; i < i1; i++) {
    int hv = cur[i];
    gb[i] = bucketStart[i] + ofs[i] - run;  // final = gb[b] + localPos
    cur[i] = run;
    run += hv;
  }
  __syncthreads();

  for (int i = tid; i < cntE; i += 256) {
    int r = erow[e0 + i];
    int c = ecol[e0 + i];
    float v = evl[e0 + i];
    int b = r >> BSHIFT;
    int p = atomicAdd(&cur[b], 1);
    rec[p]  = make_int2(((r & (BROWS - 1)) << 17) | c, __float_as_int(v));
    dstv[p] = gb[b];
  }
  __syncthreads();

  for (int i = tid; i < cntE; i += 256)
    binned[dstv[i] + i] = rec[i];
}

// ---------- per-bucket counting sort -> exact CSR (tier A, stage 2) ----------
__global__ __launch_bounds__(512) void bucket_sort_k(
    const int* __restrict__ bucketStart, const int2* __restrict__ binned,
    int2* __restrict__ pairs, int* __restrict__ startv, int* __restrict__ cnt,
    int N)
{
  __shared__ int h[BROWS], sc[BROWS], cur[BROWS];
  const int tid = threadIdx.x;
  const int bkt = blockIdx.x;
  const int s = bucketStart[bkt], e = bucketStart[bkt + 1];
  if (tid < BROWS) h[tid] = 0;
  __syncthreads();
  for (int i = s + tid; i < e; i += 512)
    atomicAdd(&h[((unsigned)binned[i].x) >> 17], 1);
  __syncthreads();
  if (tid < BROWS) sc[tid] = h[tid];
  __syncthreads();
  #pragma unroll
  for (int off = 1; off < BROWS; off <<= 1) {
    int u = (tid < BROWS && tid >= off) ? sc[tid - off] : 0;
    __syncthreads();
    if (tid < BROWS) sc[tid] += u;
    __syncthreads();
  }
  if (tid < BROWS) {
    int start = s + sc[tid] - h[tid];
    cur[tid] = start;
    int row = (bkt << BSHIFT) + tid;
    if (row < N) { startv[row] = start; cnt[row] = h[tid]; }
  }
  __syncthreads();
  for (int i = s + tid; i < e; i += 512) {
    int2 r = binned[i];
    int p = atomicAdd(&cur[((unsigned)r.x) >> 17], 1);
    pairs[p] = make_int2(r.x & 0x1ffff, r.y);
  }
}

// ---------- tier B CSR build (round-0 baseline, exact but random scatter) ----
__global__ __launch_bounds__(256) void hist_k(const int* __restrict__ erow, int* cnt, int E) {
  int e = blockIdx.x * 256 + threadIdx.x;
  if (e < E) atomicAdd(&cnt[erow[e]], 1);
}

__global__ __launch_bounds__(256) void scan1_k(const int* __restrict__ cnt, int* startv, int* bsum, int N) {
  __shared__ int s[256];
  int t = threadIdx.x, i = blockIdx.x * 256 + t;
  int v = (i < N) ? cnt[i] : 0;
  s[t] = v; __syncthreads();
  for (int off = 1; off < 256; off <<= 1) {
    int u = (t >= off) ? s[t - off] : 0;
    __syncthreads(); s[t] += u; __syncthreads();
  }
  if (i < N) startv[i] = s[t] - v;
  if (t == 255) bsum[blockIdx.x] = s[255];
}

__global__ __launch_bounds__(512) void scan2_k(const int* __restrict__ bsum, int* bsumx, int nb) {
  __shared__ int s[512];
  int t = threadIdx.x;
  int v = (t < nb) ? bsum[t] : 0;
  s[t] = v; __syncthreads();
  for (int off = 1; off < 512; off <<= 1) {
    int u = (t >= off) ? s[t - off] : 0;
    __syncthreads(); s[t] += u; __syncthreads();
  }
  if (t < nb) bsumx[t] = s[t] - v;
}

__global__ __launch_bounds__(256) void scan3_k(int* startv, const int* __restrict__ bsumx, int* cursor, int N) {
  int i = blockIdx.x * 256 + threadIdx.x;
  if (i < N) {
    int v = startv[i] + bsumx[i >> 8];
    startv[i] = v;
    cursor[i] = v;
  }
}

__global__ __launch_bounds__(256) void scatter_k(
    const int* __restrict__ erow, const int* __restrict__ ecol,
    const float* __restrict__ evl, int* cursor, int2* __restrict__ pairs, int E)
{
  int e = blockIdx.x * 256 + threadIdx.x;
  if (e < E) {
    int r = erow[e];
    int p = atomicAdd(&cursor[r], 1);
    pairs[p] = make_int2(ecol[e], __float_as_int(evl[e]));
  }
}

// ---------- CSR SpMM: one wave per row; lanes 0-31 = features ----------
// Each half-wave owns a contiguous half of the row's edges; 8 pairs + 8
// X-gathers in flight per stream. FUSE_LIN: apply relu + 32x32 linear (W,b)
// in the epilogue and write bf16. NOTE: FUSE_LIN out MUST NOT alias X (race).
template<bool FUSE_LIN>
__global__ __launch_bounds__(256) void spmm_csr_bf16_k(
    const int* __restrict__ startv, const int* __restrict__ cnt,
    const int2* __restrict__ pairs, const unsigned short* __restrict__ X,
    void* __restrict__ outp, const float* __restrict__ W,
    const float* __restrict__ b, int N)
{
  __shared__ float sW[32][33];
  __shared__ float sb[32];
  __shared__ float sAcc[4][32];
  const int tid = threadIdx.x;
  if (FUSE_LIN) {
    for (int i = tid; i < 1024; i += 256) sW[i >> 5][i & 31] = W[i];
    if (tid < 32) sb[tid] = b[tid];
    __syncthreads();
  }
  int row = blockIdx.x * 4 + (tid >> 6);
  if (row >= N) return;
  int lane = tid & 63;
  int f = lane & 31, hh = lane >> 5;
  int start = startv[row];
  int len = cnt[row];
  int half = len >> 1;
  int base = start + (hh ? half : 0);
  int n = hh ? (len - half) : half;
  float acc = 0.0f;
  int i = 0;
  for (; i + 7 < n; i += 8) {
    int2 p0 = pairs[base + i + 0];
    int2 p1 = pairs[base + i + 1];
    int2 p2 = pairs[base + i + 2];
    int2 p3 = pairs[base + i + 3];
    int2 p4 = pairs[base + i + 4];
    int2 p5 = pairs[base + i + 5];
    int2 p6 = pairs[base + i + 6];
    int2 p7 = pairs[base + i + 7];
    float x0 = bf2f(X[(size_t)p0.x * 32 + f]);
    float x1 = bf2f(X[(size_t)p1.x * 32 + f]);
    float x2 = bf2f(X[(size_t)p2.x * 32 + f]);
    float x3 = bf2f(X[(size_t)p3.x * 32 + f]);
    float x4 = bf2f(X[(size_t)p4.x * 32 + f]);
    float x5 = bf2f(X[(size_t)p5.x * 32 + f]);
    float x6 = bf2f(X[(size_t)p6.x * 32 + f]);
    float x7 = bf2f(X[(size_t)p7.x * 32 + f]);
    acc = fmaf(__int_as_float(p0.y), x0, acc);
    acc = fmaf(__int_as_float(p1.y), x1, acc);
    acc = fmaf(__int_as_float(p2.y), x2, acc);
    acc = fmaf(__int_as_float(p3.y), x3, acc);
    acc = fmaf(__int_as_float(p4.y), x4, acc);
    acc = fmaf(__int_as_float(p5.y), x5, acc);
    acc = fmaf(__int_as_float(p6.y), x6, acc);
    acc = fmaf(__int_as_float(p7.y), x7, acc);
  }
  for (; i + 3 < n; i += 4) {
    int2 p0 = pairs[base + i + 0];
    int2 p1 = pairs[base + i + 1];
    int2 p2 = pairs[base + i + 2];
    int2 p3 = pairs[base + i + 3];
    float x0 = bf2f(X[(size_t)p0.x * 32 + f]);
    float x1 = bf2f(X[(size_t)p1.x * 32 + f]);
    float x2 = bf2f(X[(size_t)p2.x * 32 + f]);
    float x3 = bf2f(X[(size_t)p3.x * 32 + f]);
    acc = fmaf(__int_as_float(p0.y), x0, acc);
    acc = fmaf(__int_as_float(p1.y), x1, acc);
    acc = fmaf(__int_as_float(p2.y), x2, acc);
    acc = fmaf(__int_as_float(p3.y), x3, acc);
  }
  for (; i < n; i++) {
    int2 p = pairs[base + i];
    acc = fmaf(__int_as_float(p.y), bf2f(X[(size_t)p.x * 32 + f]), acc);
  }
  acc += __shfl_down(acc, 32);
  if (!FUSE_LIN) {
    if (hh == 0) ((float*)outp)[(size_t)row * 32 + f] = acc;
  } else {
    // fused relu + 32x32 linear: per-wave LDS stage (wave-local RAW, no barrier)
    const int w = tid >> 6;
    if (hh == 0) sAcc[w][f] = fmaxf(acc, 0.0f);
    float part = 0.0f;
    #pragma unroll
    for (int j0 = 0; j0 < 16; j0++) {
      int j = hh * 16 + j0;
      part = fmaf(sAcc[w][j], sW[f][j], part);
    }
    part += __shfl_down(part, 32);
    if (hh == 0)
      ((unsigned short*)outp)[(size_t)row * 32 + f] = f2bf(sb[f] + part);
  }
}

// ---------- fused MFMA GRU + head, 32 nodes / block ----------
// Round-11: reverted to the round-8 version (plain sigmoid/tanh, UNSCALED
// weights). Round-10's exp2 pre-scaling cut VALU issue (67->51%) but pushed
// VGPR 84->88, crossing the 6->5 waves/SIMD boundary (Occ 29->20%) and
// REGRESSING dur 203->231us — the kernel is occupancy/latency-bound, not
// VALU-issue-bound. VGPR 84, launch_bounds (256,2); (256,4) spills.
#define NB 32

__global__ __launch_bounds__(256, 2) void gru_head_mfma(
    const float* __restrict__ acc2,   // (N,32) pre-relu graph output
    const float* __restrict__ xdyn,   // (T,N,8)
    const float* __restrict__ Wih,    // (192,40)
    const float* __restrict__ Whh,    // (192,64)
    const float* __restrict__ bih, const float* __restrict__ bhh,
    const float* __restrict__ h1W,    // (64,64)
    const float* __restrict__ h1b, const float* __restrict__ h2W,
    const float* __restrict__ h2b,
    float* __restrict__ out, int N, int T)
{
  __shared__ __align__(16) unsigned short z[2][NB][104];  // [buf][n][k] bf16
  __shared__ float s_red[2][NB][5];                       // double-buffered head partials

  const int tid  = threadIdx.x;
  const int w    = tid >> 6;       // wave 0..3
  const int lane = tid & 63;
  const int ml   = lane & 15;      // A-row / B-col within tile
  const int q    = lane >> 4;      // quad
  const int n0   = blockIdx.x * NB;

  // ---- A fragments (weights), built once; only the 9 nonzero ones ----
  bf16x8_t A_r[3], A_z[3], A_in, A_hn[2];
  {
    const int j = 16 * w + ml;
    #pragma unroll
    for (int s = 0; s < 3; s++) {
      union { bf16x8_t v; unsigned short u[8]; } tr, tz;
      #pragma unroll
      for (int jj = 0; jj < 8; jj++) {
        int k = s * 32 + q * 8 + jj;
        float vr = (k < 64) ? Whh[j * 64 + k]        : (k < 72 ? Wih[j * 40 + 32 + (k - 64)] : 0.0f);
        float vz = (k < 64) ? Whh[(64 + j) * 64 + k] : (k < 72 ? Wih[(64 + j) * 40 + 32 + (k - 64)] : 0.0f);
        tr.u[jj] = f2bf(vr);
        tz.u[jj] = f2bf(vz);
      }
      A_r[s] = tr.v; A_z[s] = tz.v;
    }
    union { bf16x8_t v; unsigned short u[8]; } ti;
    #pragma unroll
    for (int jj = 0; jj < 8; jj++) {
      int kk = q * 8 + jj;
      ti.u[jj] = f2bf((kk < 8) ? Wih[(128 + j) * 40 + 32 + kk] : 0.0f);
    }
    A_in = ti.v;
    #pragma unroll
    for (int s = 0; s < 2; s++) {
      union { bf16x8_t v; unsigned short u[8]; } th;
      #pragma unroll
      for (int jj = 0; jj < 8; jj++)
        th.u[jj] = f2bf(Whh[(128 + j) * 64 + s * 32 + q * 8 + jj]);
      A_hn[s] = th.v;
    }
  }
  bf16x8_t Ah[2];   // head h1W (64x64), wave w owns o-rows [16w,16w+16)
  #pragma unroll
  for (int s = 0; s < 2; s++) {
    union { bf16x8_t v; unsigned short u[8]; } tmp;
    #pragma unroll
    for (int jj = 0; jj < 8; jj++)
      tmp.u[jj] = f2bf(h1W[(16 * w + ml) * 64 + s * 32 + q * 8 + jj]);
    Ah[s] = tmp.v;
  }

  // per-reg persistent constants as accumulator-layout vectors (j = 16w+4q+reg)
  f32x4_t bhhn4, h1b4;
  float h2w_r[4];
  #pragma unroll
  for (int reg = 0; reg < 4; reg++) {
    int j = 16 * w + 4 * q + reg;
    bhhn4[reg] = bhh[128 + j];
    h1b4[reg]  = h1b[j];
    h2w_r[reg] = h2W[j];
  }
  const float h2b0 = h2b[0];

  // ---- stage hg = relu(acc2) bf16 into z[0] cols 0..32 ----
  {
    int nd = tid >> 3, f0 = (tid & 7) * 4;
    float4 v = *(const float4*)(acc2 + (size_t)(n0 + nd) * 32 + f0);
    uint2 pk;
    pk.x = cvt_pk_bf16(fmaxf(v.x, 0.0f), fmaxf(v.y, 0.0f));
    pk.y = cvt_pk_bf16(fmaxf(v.z, 0.0f), fmaxf(v.w, 0.0f));
    *(uint2*)&z[0][nd][f0] = pk;
  }
  __syncthreads();

  // gis = W_is @ hg^T (K=32), biases folded in
  f32x4_t gis[3][2];
  {
    bf16x8_t Ag[3];
    #pragma unroll
    for (int g = 0; g < 3; g++) {
      union { bf16x8_t v; unsigned short u[8]; } tmp;
      #pragma unroll
      for (int jj = 0; jj < 8; jj++)
        tmp.u[jj] = f2bf(Wih[(g * 64 + 16 * w + ml) * 40 + q * 8 + jj]);
      Ag[g] = tmp.v;
    }
    bf16x8_t Bg[2];
    #pragma unroll
    for (int nt = 0; nt < 2; nt++)
      Bg[nt] = *(const bf16x8_t*)&z[0][nt * 16 + ml][q * 8];
    f32x4_t zero = {0.0f, 0.0f, 0.0f, 0.0f};
    #pragma unroll
    for (int g = 0; g < 3; g++)
      #pragma unroll
      for (int nt = 0; nt < 2; nt++)
        gis[g][nt] = __builtin_amdgcn_mfma_f32_16x16x32_bf16(Ag[g], Bg[nt], zero, 0, 0, 0);
  }
  __syncthreads();   // gis B-reads complete before zeroing

  for (int i = tid; i < 2 * NB * 104 / 2; i += 256) ((unsigned int*)z)[i] = 0;
  #pragma unroll
  for (int reg = 0; reg < 4; reg++) {
    int j = 16 * w + 4 * q + reg;
    float br = bih[j] + bhh[j];
    float bz = bih[64 + j] + bhh[64 + j];
    float bn = bih[128 + j];
    #pragma unroll
    for (int nt = 0; nt < 2; nt++) {
      gis[0][nt][reg] += br;
      gis[1][nt][reg] += bz;
      gis[2][nt][reg] += bn;
    }
  }
  __syncthreads();

  float hreg[2][4] = {{0, 0, 0, 0}, {0, 0, 0, 0}};

  // prefetch xd(0)
  float4 xv = make_float4(0.f, 0.f, 0.f, 0.f);
  if (tid < 64) xv = *(const float4*)(xdyn + (size_t)n0 * 8 + tid * 4);

  for (int t = 0; t < T; t++) {
    const int b = t & 1;
    // stage xd(t) into z[b] cols 64..72; prefetch xd(t+1)
    if (tid < 64) {
      uint2 pk;
      pk.x = cvt_pk_bf16(xv.x, xv.y);
      pk.y = cvt_pk_bf16(xv.z, xv.w);
      *(uint2*)&z[b][tid >> 1][64 + (tid & 1) * 4] = pk;
      if (t + 1 < T)
        xv = *(const float4*)(xdyn + ((size_t)(t + 1) * N + n0) * 8 + tid * 4);
    }
    __syncthreads();   // S1 (the ONLY barrier per step)

    // reduce + output for step t-2
    if (t >= 2 && tid < 32) {
      float s = s_red[1 - b][tid][0] + s_red[1 - b][tid][1] +
                s_red[1 - b][tid][2] + s_red[1 - b][tid][3];
      out[(size_t)(t - 2) * N + n0 + tid] = sigmoidf_(s + h2b0);
    }

    #pragma unroll
    for (int nt = 0; nt < 2; nt++) {
      bf16x8_t B0 = *(const bf16x8_t*)&z[b][nt * 16 + ml][q * 8];
      bf16x8_t B1 = *(const bf16x8_t*)&z[b][nt * 16 + ml][32 + q * 8];
      bf16x8_t B2 = *(const bf16x8_t*)&z[b][nt * 16 + ml][64 + q * 8];

      // main GEMM (gates for step t); gis/bhh_n ride in as C-in (exact fp32 add)
      f32x4_t ar  = gis[0][nt];
      f32x4_t az  = gis[1][nt];
      f32x4_t ain = gis[2][nt];
      f32x4_t ahn = bhhn4;
      ar  = __builtin_amdgcn_mfma_f32_16x16x32_bf16(A_r[0], B0, ar, 0, 0, 0);
      az  = __builtin_amdgcn_mfma_f32_16x16x32_bf16(A_z[0], B0, az, 0, 0, 0);
      ahn = __builtin_amdgcn_mfma_f32_16x16x32_bf16(A_hn[0], B0, ahn, 0, 0, 0);
      ar  = __builtin_amdgcn_mfma_f32_16x16x32_bf16(A_r[1], B1, ar, 0, 0, 0);
      az  = __builtin_amdgcn_mfma_f32_16x16x32_bf16(A_z[1], B1, az, 0, 0, 0);
      ahn = __builtin_amdgcn_mfma_f32_16x16x32_bf16(A_hn[1], B1, ahn, 0, 0, 0);
      ar  = __builtin_amdgcn_mfma_f32_16x16x32_bf16(A_r[2], B2, ar, 0, 0, 0);
      az  = __builtin_amdgcn_mfma_f32_16x16x32_bf16(A_z[2], B2, az, 0, 0, 0);
      ain = __builtin_amdgcn_mfma_f32_16x16x32_bf16(A_in,  B2, ain, 0, 0, 0);

      // head GEMM for step t-1: B0/B1 ARE h_{t-1}; h1b rides in as C-in
      if (t >= 1) {
        f32x4_t ha = h1b4;
        ha = __builtin_amdgcn_mfma_f32_16x16x32_bf16(Ah[0], B0, ha, 0, 0, 0);
        ha = __builtin_amdgcn_mfma_f32_16x16x32_bf16(Ah[1], B1, ha, 0, 0, 0);
        float p = 0.0f;
        #pragma unroll
        for (int reg = 0; reg < 4; reg++)
          p += h2w_r[reg] * fmaxf(ha[reg], 0.0f);
        p += __shfl_xor(p, 16, 64);
        p += __shfl_xor(p, 32, 64);
        if (q == 0) s_red[b][nt * 16 + ml][w] = p;
      }

      // epilogue: gates + state update; h_t -> the OTHER buffer
      float hv[4];
      #pragma unroll
      for (int reg = 0; reg < 4; reg++) {
        float r  = sigmoidf_(ar[reg]);
        float zg = sigmoidf_(az[reg]);
        float nn = tanhf_(fmaf(r, ahn[reg], ain[reg]));
        float h  = fmaf(zg, hreg[nt][reg] - nn, nn);
        hreg[nt][reg] = h;
        hv[reg] = h;
      }
      uint2 pk;
      pk.x = cvt_pk_bf16(hv[0], hv[1]);
      pk.y = cvt_pk_bf16(hv[2], hv[3]);
      *(uint2*)&z[1 - b][nt * 16 + ml][16 * w + 4 * q] = pk;
    }
  }

  // ---- drain: head(T-1), out(T-2), out(T-1) ----
  const int bl = (T - 1) & 1;
  __syncthreads();

  if (tid < 32) {
    float s = s_red[bl][tid][0] + s_red[bl][tid][1] +
              s_red[bl][tid][2] + s_red[bl][tid][3];
    out[(size_t)(T - 2) * N + n0 + tid] = sigmoidf_(s + h2b0);
  }
  #pragma unroll
  for (int nt = 0; nt < 2; nt++) {
    bf16x8_t B0 = *(const bf16x8_t*)&z[1 - bl][nt * 16 + ml][q * 8];
    bf16x8_t B1 = *(const bf16x8_t*)&z[1 - bl][nt * 16 + ml][32 + q * 8];
    f32x4_t ha = h1b4;
    ha = __builtin_amdgcn_mfma_f32_16x16x32_bf16(Ah[0], B0, ha, 0, 0, 0);
    ha = __builtin_amdgcn_mfma_f32_16x16x32_bf16(Ah[1], B1, ha, 0, 0, 0);
    float p = 0.0f;
    #pragma unroll
    for (int reg = 0; reg < 4; reg++)
      p += h2w_r[reg] * fmaxf(ha[reg], 0.0f);
    p += __shfl_xor(p, 16, 64);
    p += __shfl_xor(p, 32, 64);
    if (q == 0) s_red[1 - bl][nt * 16 + ml][w] = p;
  }
  __syncthreads();
  if (tid < 32) {
    float s = s_red[1 - bl][tid][0] + s_red[1 - bl][tid][1] +
              s_red[1 - bl][tid][2] + s_red[1 - bl][tid][3];
    out[(size_t)(T - 1) * N + n0 + tid] = sigmoidf_(s + h2b0);
  }
}

extern "C" void kernel_launch(void* const* d_in, const int* in_sizes, int n_in,
                              void* d_out, int out_size, void* d_ws, size_t ws_size,
                              hipStream_t stream) {
  const float* Xs   = (const float*)d_in[0];
  const float* Xd   = (const float*)d_in[1];
  const int*   erow = (const int*)d_in[2];
  const int*   ecol = (const int*)d_in[3];
  const float* evl  = (const float*)d_in[4];
  const float* g1W  = (const float*)d_in[5];
  const float* g1b  = (const float*)d_in[6];
  const float* g2W  = (const float*)d_in[7];
  const float* g2b  = (const float*)d_in[8];
  const float* Wih  = (const float*)d_in[9];
  const float* Whh  = (const float*)d_in[10];
  const float* bih  = (const float*)d_in[11];
  const float* bhh  = (const float*)d_in[12];
  const float* h1W  = (const float*)d_in[13];
  const float* h1b  = (const float*)d_in[14];
  const float* h2W  = (const float*)d_in[15];
  const float* h2b  = (const float*)d_in[16];

  const int N = in_sizes[0] / 32;
  const int E = in_sizes[2];
  const int T = in_sizes[1] / (N * 8);

  float* out  = (float*)d_out;
  char*  base = (char*)d_ws;
  float* buf0 = (float*)base;                     // N*32 f32 (also aliased as bf16)
  float* buf1 = buf0 + (size_t)N * 32;            // N*32 f32 (also aliased as bf16)
  int*   cnt    = (int*)(buf1 + (size_t)N * 32);  // N
  int*   startv = cnt + N;                        // N
  int*   cursor = startv + N;                     // N (tier B only)
  int*   bsum   = cursor + N;                     // 512 (tier B only)
  int*   bsumx  = bsum + 512;                     // 512 (tier B only)
  unsigned short* buf0h = (unsigned short*)buf0;  // bf16 view of buf0
  unsigned short* buf1h = (unsigned short*)buf1;  // bf16 view of buf1

  const int nBuckets = (N + BROWS - 1) >> BSHIFT;
  const int nbBin    = (E + EPB - 1) / EPB;

  int* bucketStart = bsumx + 512;                       // nBuckets+1
  int* bucketTotal = bucketStart + nBuckets + 1;        // nBuckets
  int* blockHist   = bucketTotal + nBuckets;            // nbBin*nBuckets
  char* pp = (char*)(blockHist + (size_t)nbBin * nBuckets);
  pp = (char*)(((uintptr_t)pp + 15) & ~(uintptr_t)15);
  int2* pairs  = (int2*)pp;                             // E (both tiers)
  int2* binned = pairs + E;                             // E (tier A only)

  const size_t neededA = (size_t)((char*)(binned + E) - base);
  const size_t neededB = (size_t)((char*)(pairs + E) - base);

  const int linBlocks = (N + 7) / 8;
  const int eBlocks   = (E + 255) / 256;
  const int nb1       = (N + 255) / 256;

  const bool tierA = (ws_size >= neededA) && (nBuckets <= MAXBUCKETS) &&
                     (N <= (1 << 17));
  const bool tierB = !tierA && (ws_size >= neededB);

  if (tierA) {
    // lin32-g1 and hist_bin merged (independent subgraphs, one launch)
    lin_hist_k<<<linBlocks + nbBin, 256, 0, stream>>>(
        Xs, g1W, g1b, buf0h, N, linBlocks, erow, blockHist, E, nBuckets);

    colscan_k<<<nBuckets, 128, 0, stream>>>(blockHist, bucketTotal, nbBin, nBuckets);
    bucketstart_k<<<1, 1024, 0, stream>>>(bucketTotal, bucketStart, nBuckets);
    scatter_stage_k<<<nbBin, 256, 0, stream>>>(erow, ecol, evl, blockHist,
                                               bucketStart, binned, E, nBuckets);
    bucket_sort_k<<<nBuckets, 512, 0, stream>>>(bucketStart, binned, pairs,
                                                startv, cnt, N);

    // spmm1 fused relu+lin32-g2: read buf0h, write bf16 -> buf1h (NO alias)
    spmm_csr_bf16_k<true><<<(N + 3) / 4, 256, 0, stream>>>(
        startv, cnt, pairs, buf0h, buf1h, g2W, g2b, N);
    // spmm2: read buf1h, write f32 -> buf0
    spmm_csr_bf16_k<false><<<(N + 3) / 4, 256, 0, stream>>>(
        startv, cnt, pairs, buf1h, buf0, nullptr, nullptr, N);
  } else if (tierB) {
    // round-0 baseline CSR build (exact, random scatter)
    lin32_kernel<false, true><<<linBlocks, 256, 0, stream>>>(Xs, g1W, g1b, buf0h, N);

    hipMemsetAsync(cnt, 0, (size_t)N * sizeof(int), stream);
    hist_k<<<eBlocks, 256, 0, stream>>>(erow, cnt, E);
    scan1_k<<<nb1, 256, 0, stream>>>(cnt, startv, bsum, N);
    scan2_k<<<1, 512, 0, stream>>>(bsum, bsumx, nb1);
    scan3_k<<<nb1, 256, 0, stream>>>(startv, bsumx, cursor, N);
    scatter_k<<<eBlocks, 256, 0, stream>>>(erow, ecol, evl, cursor, pairs, E);

    spmm_csr_bf16_k<true><<<(N + 3) / 4, 256, 0, stream>>>(
        startv, cnt, pairs, buf0h, buf1h, g2W, g2b, N);
    spmm_csr_bf16_k<false><<<(N + 3) / 4, 256, 0, stream>>>(
        startv, cnt, pairs, buf1h, buf0, nullptr, nullptr, N);
  } else {
    // atomic fallback
    lin32_kernel<false, false><<<linBlocks, 256, 0, stream>>>(Xs, g1W, g1b, buf1, N);
    const int spmmBlocks = (int)(((long)E * 8 + 255) / 256);
    hipMemsetAsync(buf0, 0, (size_t)N * 32 * sizeof(float), stream);
    spmm_kernel<<<spmmBlocks, 256, 0, stream>>>(erow, ecol, evl, buf1, buf0, E);
    lin32_kernel<true, false><<<linBlocks, 256, 0, stream>>>(buf0, g2W, g2b, buf1, N);
    hipMemsetAsync(buf0, 0, (size_t)N * 32 * sizeof(float), stream);
    spmm_kernel<<<spmmBlocks, 256, 0, stream>>>(erow, ecol, evl, buf1, buf0, E);
  }

  // fused MFMA GRU + head (acc2 = buf0, f32)
  gru_head_mfma<<<N / NB, 256, 0, stream>>>(buf0, Xd, Wih, Whh, bih, bhh,
                                            h1W, h1b, h2W, h2b, out, N, T);
}

// Round 12
// 571.824 us; speedup vs baseline: 1.0932x; 1.0109x over previous
//
#include <hip/hip_runtime.h>
#include <math.h>

typedef short bf16x8_t __attribute__((ext_vector_type(8)));
typedef float f32x4_t  __attribute__((ext_vector_type(4)));

__device__ __forceinline__ float fast_rcp(float x) { return __builtin_amdgcn_rcpf(x); }
__device__ __forceinline__ float sigmoidf_(float x) {
  return fast_rcp(1.0f + __expf(-x));
}
__device__ __forceinline__ float tanhf_(float x) {
  // tanh(x) = 1 - 2/(e^{2x}+1); inf-safe without clamps (exp->inf => rcp->0 => 1)
  return fmaf(-2.0f, fast_rcp(__expf(2.0f * x) + 1.0f), 1.0f);
}
__device__ __forceinline__ unsigned short f2bf(float f) {
  unsigned int u = __float_as_uint(f);
  unsigned int r = (u + 0x7fffu + ((u >> 16) & 1u)) >> 16;
  return (unsigned short)r;
}
__device__ __forceinline__ float bf2f(unsigned short u) {
  return __uint_as_float(((unsigned int)u) << 16);
}
// 2x f32 -> packed bf16 in one VALU op (gfx950; no builtin, inline asm per T12)
__device__ __forceinline__ unsigned int cvt_pk_bf16(float a, float b) {
  unsigned int d;
  asm("v_cvt_pk_bf16_f32 %0, %1, %2" : "=v"(d) : "v"(a), "v"(b));
  return d;
}

// ---------- dense 32-in/32-out linear: out = [relu?](X) @ W^T + b ----------
template<bool RELU_IN, bool OUT_BF16>
__global__ __launch_bounds__(256) void lin32_kernel(
    const float* __restrict__ X, const float* __restrict__ W,
    const float* __restrict__ b, void* __restrict__ outp, int N)
{
  __shared__ float sW[32][33];
  __shared__ float sb[32];
  __shared__ float sX[8][33];
  const int tid = threadIdx.x;
  for (int i = tid; i < 1024; i += 256) sW[i >> 5][i & 31] = W[i];
  if (tid < 32) sb[tid] = b[tid];
  const int n0 = blockIdx.x * 8;
  {
    float v = X[(size_t)n0 * 32 + tid];
    if (RELU_IN) v = fmaxf(v, 0.0f);
    sX[tid >> 5][tid & 31] = v;
  }
  __syncthreads();
  const int ln = tid >> 5, f = tid & 31;
  float acc = sb[f];
  #pragma unroll
  for (int j = 0; j < 32; j++) acc += sX[ln][j] * sW[f][j];
  if (OUT_BF16) ((unsigned short*)outp)[(size_t)n0 * 32 + tid] = f2bf(acc);
  else          ((float*)outp)[(size_t)n0 * 32 + tid] = acc;
}

// ---------- fallback SpMM (atomics, fp32) ----------
__global__ __launch_bounds__(256) void spmm_kernel(
    const int* __restrict__ erow, const int* __restrict__ ecol,
    const float* __restrict__ eval, const float* __restrict__ X,
    float* __restrict__ out, int E)
{
  const long gid = (long)blockIdx.x * 256 + threadIdx.x;
  const int e = (int)(gid >> 3);
  const int q = (int)(gid & 7);
  if (e >= E) return;
  const int r = erow[e], c = ecol[e];
  const float v = eval[e];
  const float4 x = *(const float4*)(X + (size_t)c * 32 + q * 4);
  float* o = out + (size_t)r * 32 + q * 4;
  atomicAdd(o + 0, v * x.x);
  atomicAdd(o + 1, v * x.y);
  atomicAdd(o + 2, v * x.z);
  atomicAdd(o + 3, v * x.w);
}

// ---------- 128-row bucket multisplit (tier A CSR build, stage 1) ----------
#define BROWS 128
#define BSHIFT 7
#define EPB 4096            // edges per binning block
#define MAXBUCKETS 1024

// lin32-g1 and hist_bin merged (independent subgraphs, one launch).
// Round-12: hist also saves raw counts to blockCnt — colscan destroys
// blockHist (converts to offsets), and scatter_stage was re-histogramming
// all edges (12.8MB read + 3.2M LDS atomics) just to recover these counts.
__global__ __launch_bounds__(256) void lin_hist_k(
    const float* __restrict__ X, const float* __restrict__ W,
    const float* __restrict__ b, unsigned short* __restrict__ outp,
    int N, int linBlocks,
    const int* __restrict__ erow, int* __restrict__ blockHist,
    int* __restrict__ blockCnt, int E, int nBuckets)
{
  __shared__ float sW[32][33];
  __shared__ float sb[32];
  __shared__ float sX[8][33];
  __shared__ int h[MAXBUCKETS];
  const int tid = threadIdx.x;
  if ((int)blockIdx.x < linBlocks) {
    for (int i = tid; i < 1024; i += 256) sW[i >> 5][i & 31] = W[i];
    if (tid < 32) sb[tid] = b[tid];
    const int n0 = blockIdx.x * 8;
    sX[tid >> 5][tid & 31] = X[(size_t)n0 * 32 + tid];
    __syncthreads();
    const int ln = tid >> 5, f = tid & 31;
    float acc = sb[f];
    #pragma unroll
    for (int j = 0; j < 32; j++) acc += sX[ln][j] * sW[f][j];
    outp[(size_t)n0 * 32 + tid] = f2bf(acc);
  } else {
    const int bid = blockIdx.x - linBlocks;
    for (int i = tid; i < nBuckets; i += 256) h[i] = 0;
    __syncthreads();
    const int e0 = bid * EPB;
    const int cnt = min(E - e0, EPB);
    for (int i = tid; i < cnt; i += 256)
      atomicAdd(&h[erow[e0 + i] >> BSHIFT], 1);
    __syncthreads();
    int* o = blockHist + (size_t)bid * nBuckets;
    int* c = blockCnt + (size_t)bid * nBuckets;
    for (int i = tid; i < nBuckets; i += 256) { int v = h[i]; o[i] = v; c[i] = v; }
  }
}

// colscan_k: one block per bucket column; parallel replacement for the old
// single-block serial scan (was ~94us on one CU).
__global__ __launch_bounds__(128) void colscan_k(
    int* __restrict__ blockHist, int* __restrict__ bucketTotal,
    int nb, int nBuckets)
{
  __shared__ int s[128];
  const int b = blockIdx.x;          // bucket column
  const int t = threadIdx.x;
  const int k = (nb + 127) >> 7;     // segment length per thread
  const int i0 = t * k, i1 = min(nb, i0 + k);
  int p = 0;
  for (int i = i0; i < i1; i++) p += blockHist[(size_t)i * nBuckets + b];
  s[t] = p;
  __syncthreads();
  #pragma unroll
  for (int off = 1; off < 128; off <<= 1) {
    int u = (t >= off) ? s[t - off] : 0;
    __syncthreads(); s[t] += u; __syncthreads();
  }
  int run = s[t] - p;                // exclusive prefix for this segment
  if (t == 127) bucketTotal[b] = s[127];
  for (int i = i0; i < i1; i++) {
    int* q = &blockHist[(size_t)i * nBuckets + b];
    int v = *q;
    *q = run;
    run += v;
  }
}

// one block: exclusive scan of bucket totals -> bucketStart[0..nBuckets]
__global__ __launch_bounds__(1024) void bucketstart_k(
    const int* __restrict__ bucketTotal, int* __restrict__ bucketStart,
    int nBuckets)
{
  __shared__ int s[1024];
  const int b = threadIdx.x;
  int v = (b < nBuckets) ? bucketTotal[b] : 0;
  s[b] = v;
  __syncthreads();
  for (int off = 1; off < 1024; off <<= 1) {
    int u = (b >= off) ? s[b - off] : 0;
    __syncthreads(); s[b] += u; __syncthreads();
  }
  if (b < nBuckets) bucketStart[b] = s[b] - v;
  if (b == nBuckets - 1) bucketStart[nBuckets] = s[b];
}

// ---------- LDS-staged multisplit scatter ----------
// Round-12: (a) counts come from blockCnt (saved by lin_hist) — no
// re-histogram pass; (b) dstv stores ushort bucket-ids (write-out resolves
// gb[dstv[i]] from LDS) — LDS 57KB->49KB -> 3 blocks/CU.
// record = ((rowLocal(7b) << 17) | col(17b), val_f32) : 8B
__global__ __launch_bounds__(256) void scatter_stage_k(
    const int* __restrict__ erow, const int* __restrict__ ecol,
    const float* __restrict__ evl, const int* __restrict__ blockOfs,
    const int* __restrict__ blockCnt,
    const int* __restrict__ bucketStart, int2* __restrict__ binned,
    int E, int nBuckets)
{
  __shared__ int2 rec[EPB];            // 32KB
  __shared__ unsigned short dstv[EPB]; // 8KB  (bucket id of record)
  __shared__ int  cur[MAXBUCKETS];     // 4KB  (count -> localStart -> cursor)
  __shared__ int  gb[MAXBUCKETS];      // 4KB  (final = gb[b] + localPos)
  __shared__ int  part[256];           // 1KB
  const int tid = threadIdx.x;
  const int e0 = blockIdx.x * EPB;
  const int cntE = min(E - e0, EPB);
  const int* ofs = blockOfs + (size_t)blockIdx.x * nBuckets;
  const int* cnr = blockCnt + (size_t)blockIdx.x * nBuckets;

  // load precomputed counts (replaces the atomic histogram pass)
  for (int i = tid; i < nBuckets; i += 256) cur[i] = cnr[i];
  __syncthreads();

  const int k = (nBuckets + 255) >> 8;
  const int i0 = tid * k, i1 = min(i0 + k, nBuckets);
  int s = 0;
  for (int i = i0; i < i1; i++) s += cur[i];
  part[tid] = s;
  __syncthreads();
  for (int off = 1; off < 256; off <<= 1) {
    int u = (tid >= off) ? part[tid - off] : 0;
    __syncthreads(); part[tid] += u; __syncthreads();
  }
  int run = part[tid] - s;
  for (int i = i0; i < i1; i++) {
    int hv = cur[i];
    gb[i] = bucketStart[i] + ofs[i] - run;  // final = gb[b] + localPos
    cur[i] = run;                           // cursor = localStart
    run += hv;
  }
  __syncthreads();

  // scatter into LDS, bucket-sorted
  for (int i = tid; i < cntE; i += 256) {
    int r = erow[e0 + i];
    int c = ecol[e0 + i];
    float v = evl[e0 + i];
    int b = r >> BSHIFT;
    int p = atomicAdd(&cur[b], 1);
    rec[p]  = make_int2(((r & (BROWS - 1)) << 17) | c, __float_as_int(v));
    dstv[p] = (unsigned short)b;
  }
  __syncthreads();

  // coalesced write-out: consecutive lanes -> consecutive segment positions
  for (int i = tid; i < cntE; i += 256)
    binned[gb[dstv[i]] + i] = rec[i];
}

// ---------- per-bucket counting sort -> exact CSR (tier A, stage 2) ----------
__global__ __launch_bounds__(512) void bucket_sort_k(
    const int* __restrict__ bucketStart, const int2* __restrict__ binned,
    int2* __restrict__ pairs, int* __restrict__ startv, int* __restrict__ cnt,
    int N)
{
  __shared__ int h[BROWS], sc[BROWS], cur[BROWS];
  const int tid = threadIdx.x;
  const int bkt = blockIdx.x;
  const int s = bucketStart[bkt], e = bucketStart[bkt + 1];
  if (tid < BROWS) h[tid] = 0;
  __syncthreads();
  for (int i = s + tid; i < e; i += 512)
    atomicAdd(&h[((unsigned)binned[i].x) >> 17], 1);
  __syncthreads();
  if (tid < BROWS) sc[tid] = h[tid];
  __syncthreads();
  #pragma unroll
  for (int off = 1; off < BROWS; off <<= 1) {
    int u = (tid < BROWS && tid >= off) ? sc[tid - off] : 0;
    __syncthreads();
    if (tid < BROWS) sc[tid] += u;
    __syncthreads();
  }
  if (tid < BROWS) {
    int start = s + sc[tid] - h[tid];
    cur[tid] = start;
    int row = (bkt << BSHIFT) + tid;
    if (row < N) { startv[row] = start; cnt[row] = h[tid]; }
  }
  __syncthreads();
  for (int i = s + tid; i < e; i += 512) {
    int2 r = binned[i];
    int p = atomicAdd(&cur[((unsigned)r.x) >> 17], 1);
    pairs[p] = make_int2(r.x & 0x1ffff, r.y);
  }
}

// ---------- tier B CSR build (round-0 baseline, exact but random scatter) ----
__global__ __launch_bounds__(256) void hist_k(const int* __restrict__ erow, int* cnt, int E) {
  int e = blockIdx.x * 256 + threadIdx.x;
  if (e < E) atomicAdd(&cnt[erow[e]], 1);
}

__global__ __launch_bounds__(256) void scan1_k(const int* __restrict__ cnt, int* startv, int* bsum, int N) {
  __shared__ int s[256];
  int t = threadIdx.x, i = blockIdx.x * 256 + t;
  int v = (i < N) ? cnt[i] : 0;
  s[t] = v; __syncthreads();
  for (int off = 1; off < 256; off <<= 1) {
    int u = (t >= off) ? s[t - off] : 0;
    __syncthreads(); s[t] += u; __syncthreads();
  }
  if (i < N) startv[i] = s[t] - v;
  if (t == 255) bsum[blockIdx.x] = s[255];
}

__global__ __launch_bounds__(512) void scan2_k(const int* __restrict__ bsum, int* bsumx, int nb) {
  __shared__ int s[512];
  int t = threadIdx.x;
  int v = (t < nb) ? bsum[t] : 0;
  s[t] = v; __syncthreads();
  for (int off = 1; off < 512; off <<= 1) {
    int u = (t >= off) ? s[t - off] : 0;
    __syncthreads(); s[t] += u; __syncthreads();
  }
  if (t < nb) bsumx[t] = s[t] - v;
}

__global__ __launch_bounds__(256) void scan3_k(int* startv, const int* __restrict__ bsumx, int* cursor, int N) {
  int i = blockIdx.x * 256 + threadIdx.x;
  if (i < N) {
    int v = startv[i] + bsumx[i >> 8];
    startv[i] = v;
    cursor[i] = v;
  }
}

__global__ __launch_bounds__(256) void scatter_k(
    const int* __restrict__ erow, const int* __restrict__ ecol,
    const float* __restrict__ evl, int* cursor, int2* __restrict__ pairs, int E)
{
  int e = blockIdx.x * 256 + threadIdx.x;
  if (e < E) {
    int r = erow[e];
    int p = atomicAdd(&cursor[r], 1);
    pairs[p] = make_int2(ecol[e], __float_as_int(evl[e]));
  }
}

// ---------- CSR SpMM: one wave per row; lanes 0-31 = features ----------
// Each half-wave owns a contiguous half of the row's edges; 8 pairs + 8
// X-gathers in flight per stream. FUSE_LIN: apply relu + 32x32 linear (W,b)
// in the epilogue and write bf16. NOTE: FUSE_LIN out MUST NOT alias X (race).
template<bool FUSE_LIN>
__global__ __launch_bounds__(256) void spmm_csr_bf16_k(
    const int* __restrict__ startv, const int* __restrict__ cnt,
    const int2* __restrict__ pairs, const unsigned short* __restrict__ X,
    void* __restrict__ outp, const float* __restrict__ W,
    const float* __restrict__ b, int N)
{
  __shared__ float sW[32][33];
  __shared__ float sb[32];
  __shared__ float sAcc[4][32];
  const int tid = threadIdx.x;
  if (FUSE_LIN) {
    for (int i = tid; i < 1024; i += 256) sW[i >> 5][i & 31] = W[i];
    if (tid < 32) sb[tid] = b[tid];
    __syncthreads();
  }
  int row = blockIdx.x * 4 + (tid >> 6);
  if (row >= N) return;
  int lane = tid & 63;
  int f = lane & 31, hh = lane >> 5;
  int start = startv[row];
  int len = cnt[row];
  int half = len >> 1;
  int base = start + (hh ? half : 0);
  int n = hh ? (len - half) : half;
  float acc = 0.0f;
  int i = 0;
  for (; i + 7 < n; i += 8) {
    int2 p0 = pairs[base + i + 0];
    int2 p1 = pairs[base + i + 1];
    int2 p2 = pairs[base + i + 2];
    int2 p3 = pairs[base + i + 3];
    int2 p4 = pairs[base + i + 4];
    int2 p5 = pairs[base + i + 5];
    int2 p6 = pairs[base + i + 6];
    int2 p7 = pairs[base + i + 7];
    float x0 = bf2f(X[(size_t)p0.x * 32 + f]);
    float x1 = bf2f(X[(size_t)p1.x * 32 + f]);
    float x2 = bf2f(X[(size_t)p2.x * 32 + f]);
    float x3 = bf2f(X[(size_t)p3.x * 32 + f]);
    float x4 = bf2f(X[(size_t)p4.x * 32 + f]);
    float x5 = bf2f(X[(size_t)p5.x * 32 + f]);
    float x6 = bf2f(X[(size_t)p6.x * 32 + f]);
    float x7 = bf2f(X[(size_t)p7.x * 32 + f]);
    acc = fmaf(__int_as_float(p0.y), x0, acc);
    acc = fmaf(__int_as_float(p1.y), x1, acc);
    acc = fmaf(__int_as_float(p2.y), x2, acc);
    acc = fmaf(__int_as_float(p3.y), x3, acc);
    acc = fmaf(__int_as_float(p4.y), x4, acc);
    acc = fmaf(__int_as_float(p5.y), x5, acc);
    acc = fmaf(__int_as_float(p6.y), x6, acc);
    acc = fmaf(__int_as_float(p7.y), x7, acc);
  }
  for (; i + 3 < n; i += 4) {
    int2 p0 = pairs[base + i + 0];
    int2 p1 = pairs[base + i + 1];
    int2 p2 = pairs[base + i + 2];
    int2 p3 = pairs[base + i + 3];
    float x0 = bf2f(X[(size_t)p0.x * 32 + f]);
    float x1 = bf2f(X[(size_t)p1.x * 32 + f]);
    float x2 = bf2f(X[(size_t)p2.x * 32 + f]);
    float x3 = bf2f(X[(size_t)p3.x * 32 + f]);
    acc = fmaf(__int_as_float(p0.y), x0, acc);
    acc = fmaf(__int_as_float(p1.y), x1, acc);
    acc = fmaf(__int_as_float(p2.y), x2, acc);
    acc = fmaf(__int_as_float(p3.y), x3, acc);
  }
  for (; i < n; i++) {
    int2 p = pairs[base + i];
    acc = fmaf(__int_as_float(p.y), bf2f(X[(size_t)p.x * 32 + f]), acc);
  }
  acc += __shfl_down(acc, 32);
  if (!FUSE_LIN) {
    if (hh == 0) ((float*)outp)[(size_t)row * 32 + f] = acc;
  } else {
    // fused relu + 32x32 linear: per-wave LDS stage (wave-local RAW, no barrier)
    const int w = tid >> 6;
    if (hh == 0) sAcc[w][f] = fmaxf(acc, 0.0f);
    float part = 0.0f;
    #pragma unroll
    for (int j0 = 0; j0 < 16; j0++) {
      int j = hh * 16 + j0;
      part = fmaf(sAcc[w][j], sW[f][j], part);
    }
    part += __shfl_down(part, 32);
    if (hh == 0)
      ((unsigned short*)outp)[(size_t)row * 32 + f] = f2bf(sb[f] + part);
  }
}

// ---------- fused MFMA GRU + head, 32 nodes / block ----------
// (UNCHANGED since round-8/11 — proven 203.5us reference. Plain sigmoid/tanh,
// unscaled weights; exp2-prescaling pushed VGPR 84->88, crossing the 6->5
// waves/SIMD boundary and regressing to 231us. VGPR 84, launch_bounds
// (256,2); (256,4) spills catastrophically.)
#define NB 32

__global__ __launch_bounds__(256, 2) void gru_head_mfma(
    const float* __restrict__ acc2,   // (N,32) pre-relu graph output
    const float* __restrict__ xdyn,   // (T,N,8)
    const float* __restrict__ Wih,    // (192,40)
    const float* __restrict__ Whh,    // (192,64)
    const float* __restrict__ bih, const float* __restrict__ bhh,
    const float* __restrict__ h1W,    // (64,64)
    const float* __restrict__ h1b, const float* __restrict__ h2W,
    const float* __restrict__ h2b,
    float* __restrict__ out, int N, int T)
{
  __shared__ __align__(16) unsigned short z[2][NB][104];  // [buf][n][k] bf16
  __shared__ float s_red[2][NB][5];                       // double-buffered head partials

  const int tid  = threadIdx.x;
  const int w    = tid >> 6;       // wave 0..3
  const int lane = tid & 63;
  const int ml   = lane & 15;      // A-row / B-col within tile
  const int q    = lane >> 4;      // quad
  const int n0   = blockIdx.x * NB;

  // ---- A fragments (weights), built once; only the 9 nonzero ones ----
  bf16x8_t A_r[3], A_z[3], A_in, A_hn[2];
  {
    const int j = 16 * w + ml;
    #pragma unroll
    for (int s = 0; s < 3; s++) {
      union { bf16x8_t v; unsigned short u[8]; } tr, tz;
      #pragma unroll
      for (int jj = 0; jj < 8; jj++) {
        int k = s * 32 + q * 8 + jj;
        float vr = (k < 64) ? Whh[j * 64 + k]        : (k < 72 ? Wih[j * 40 + 32 + (k - 64)] : 0.0f);
        float vz = (k < 64) ? Whh[(64 + j) * 64 + k] : (k < 72 ? Wih[(64 + j) * 40 + 32 + (k - 64)] : 0.0f);
        tr.u[jj] = f2bf(vr);
        tz.u[jj] = f2bf(vz);
      }
      A_r[s] = tr.v; A_z[s] = tz.v;
    }
    union { bf16x8_t v; unsigned short u[8]; } ti;
    #pragma unroll
    for (int jj = 0; jj < 8; jj++) {
      int kk = q * 8 + jj;
      ti.u[jj] = f2bf((kk < 8) ? Wih[(128 + j) * 40 + 32 + kk] : 0.0f);
    }
    A_in = ti.v;
    #pragma unroll
    for (int s = 0; s < 2; s++) {
      union { bf16x8_t v; unsigned short u[8]; } th;
      #pragma unroll
      for (int jj = 0; jj < 8; jj++)
        th.u[jj] = f2bf(Whh[(128 + j) * 64 + s * 32 + q * 8 + jj]);
      A_hn[s] = th.v;
    }
  }
  bf16x8_t Ah[2];   // head h1W (64x64), wave w owns o-rows [16w,16w+16)
  #pragma unroll
  for (int s = 0; s < 2; s++) {
    union { bf16x8_t v; unsigned short u[8]; } tmp;
    #pragma unroll
    for (int jj = 0; jj < 8; jj++)
      tmp.u[jj] = f2bf(h1W[(16 * w + ml) * 64 + s * 32 + q * 8 + jj]);
    Ah[s] = tmp.v;
  }

  // per-reg persistent constants as accumulator-layout vectors (j = 16w+4q+reg)
  f32x4_t bhhn4, h1b4;
  float h2w_r[4];
  #pragma unroll
  for (int reg = 0; reg < 4; reg++) {
    int j = 16 * w + 4 * q + reg;
    bhhn4[reg] = bhh[128 + j];
    h1b4[reg]  = h1b[j];
    h2w_r[reg] = h2W[j];
  }
  const float h2b0 = h2b[0];

  // ---- stage hg = relu(acc2) bf16 into z[0] cols 0..32 ----
  {
    int nd = tid >> 3, f0 = (tid & 7) * 4;
    float4 v = *(const float4*)(acc2 + (size_t)(n0 + nd) * 32 + f0);
    uint2 pk;
    pk.x = cvt_pk_bf16(fmaxf(v.x, 0.0f), fmaxf(v.y, 0.0f));
    pk.y = cvt_pk_bf16(fmaxf(v.z, 0.0f), fmaxf(v.w, 0.0f));
    *(uint2*)&z[0][nd][f0] = pk;
  }
  __syncthreads();

  // gis = W_is @ hg^T (K=32), biases folded in
  f32x4_t gis[3][2];
  {
    bf16x8_t Ag[3];
    #pragma unroll
    for (int g = 0; g < 3; g++) {
      union { bf16x8_t v; unsigned short u[8]; } tmp;
      #pragma unroll
      for (int jj = 0; jj < 8; jj++)
        tmp.u[jj] = f2bf(Wih[(g * 64 + 16 * w + ml) * 40 + q * 8 + jj]);
      Ag[g] = tmp.v;
    }
    bf16x8_t Bg[2];
    #pragma unroll
    for (int nt = 0; nt < 2; nt++)
      Bg[nt] = *(const bf16x8_t*)&z[0][nt * 16 + ml][q * 8];
    f32x4_t zero = {0.0f, 0.0f, 0.0f, 0.0f};
    #pragma unroll
    for (int g = 0; g < 3; g++)
      #pragma unroll
      for (int nt = 0; nt < 2; nt++)
        gis[g][nt] = __builtin_amdgcn_mfma_f32_16x16x32_bf16(Ag[g], Bg[nt], zero, 0, 0, 0);
  }
  __syncthreads();   // gis B-reads complete before zeroing

  for (int i = tid; i < 2 * NB * 104 / 2; i += 256) ((unsigned int*)z)[i] = 0;
  #pragma unroll
  for (int reg = 0; reg < 4; reg++) {
    int j = 16 * w + 4 * q + reg;
    float br = bih[j] + bhh[j];
    float bz = bih[64 + j] + bhh[64 + j];
    float bn = bih[128 + j];
    #pragma unroll
    for (int nt = 0; nt < 2; nt++) {
      gis[0][nt][reg] += br;
      gis[1][nt][reg] += bz;
      gis[2][nt][reg] += bn;
    }
  }
  __syncthreads();

  float hreg[2][4] = {{0, 0, 0, 0}, {0, 0, 0, 0}};

  // prefetch xd(0)
  float4 xv = make_float4(0.f, 0.f, 0.f, 0.f);
  if (tid < 64) xv = *(const float4*)(xdyn + (size_t)n0 * 8 + tid * 4);

  for (int t = 0; t < T; t++) {
    const int b = t & 1;
    // stage xd(t) into z[b] cols 64..72; prefetch xd(t+1)
    if (tid < 64) {
      uint2 pk;
      pk.x = cvt_pk_bf16(xv.x, xv.y);
      pk.y = cvt_pk_bf16(xv.z, xv.w);
      *(uint2*)&z[b][tid >> 1][64 + (tid & 1) * 4] = pk;
      if (t + 1 < T)
        xv = *(const float4*)(xdyn + ((size_t)(t + 1) * N + n0) * 8 + tid * 4);
    }
    __syncthreads();   // S1 (the ONLY barrier per step)

    // reduce + output for step t-2
    if (t >= 2 && tid < 32) {
      float s = s_red[1 - b][tid][0] + s_red[1 - b][tid][1] +
                s_red[1 - b][tid][2] + s_red[1 - b][tid][3];
      out[(size_t)(t - 2) * N + n0 + tid] = sigmoidf_(s + h2b0);
    }

    #pragma unroll
    for (int nt = 0; nt < 2; nt++) {
      bf16x8_t B0 = *(const bf16x8_t*)&z[b][nt * 16 + ml][q * 8];
      bf16x8_t B1 = *(const bf16x8_t*)&z[b][nt * 16 + ml][32 + q * 8];
      bf16x8_t B2 = *(const bf16x8_t*)&z[b][nt * 16 + ml][64 + q * 8];

      // main GEMM (gates for step t); gis/bhh_n ride in as C-in (exact fp32 add)
      f32x4_t ar  = gis[0][nt];
      f32x4_t az  = gis[1][nt];
      f32x4_t ain = gis[2][nt];
      f32x4_t ahn = bhhn4;
      ar  = __builtin_amdgcn_mfma_f32_16x16x32_bf16(A_r[0], B0, ar, 0, 0, 0);
      az  = __builtin_amdgcn_mfma_f32_16x16x32_bf16(A_z[0], B0, az, 0, 0, 0);
      ahn = __builtin_amdgcn_mfma_f32_16x16x32_bf16(A_hn[0], B0, ahn, 0, 0, 0);
      ar  = __builtin_amdgcn_mfma_f32_16x16x32_bf16(A_r[1], B1, ar, 0, 0, 0);
      az  = __builtin_amdgcn_mfma_f32_16x16x32_bf16(A_z[1], B1, az, 0, 0, 0);
      ahn = __builtin_amdgcn_mfma_f32_16x16x32_bf16(A_hn[1], B1, ahn, 0, 0, 0);
      ar  = __builtin_amdgcn_mfma_f32_16x16x32_bf16(A_r[2], B2, ar, 0, 0, 0);
      az  = __builtin_amdgcn_mfma_f32_16x16x32_bf16(A_z[2], B2, az, 0, 0, 0);
      ain = __builtin_amdgcn_mfma_f32_16x16x32_bf16(A_in,  B2, ain, 0, 0, 0);

      // head GEMM for step t-1: B0/B1 ARE h_{t-1}; h1b rides in as C-in
      if (t >= 1) {
        f32x4_t ha = h1b4;
        ha = __builtin_amdgcn_mfma_f32_16x16x32_bf16(Ah[0], B0, ha, 0, 0, 0);
        ha = __builtin_amdgcn_mfma_f32_16x16x32_bf16(Ah[1], B1, ha, 0, 0, 0);
        float p = 0.0f;
        #pragma unroll
        for (int reg = 0; reg < 4; reg++)
          p += h2w_r[reg] * fmaxf(ha[reg], 0.0f);
        p += __shfl_xor(p, 16, 64);
        p += __shfl_xor(p, 32, 64);
        if (q == 0) s_red[b][nt * 16 + ml][w] = p;
      }

      // epilogue: gates + state update; h_t -> the OTHER buffer
      float hv[4];
      #pragma unroll
      for (int reg = 0; reg < 4; reg++) {
        float r  = sigmoidf_(ar[reg]);
        float zg = sigmoidf_(az[reg]);
        float nn = tanhf_(fmaf(r, ahn[reg], ain[reg]));
        float h  = fmaf(zg, hreg[nt][reg] - nn, nn);
        hreg[nt][reg] = h;
        hv[reg] = h;
      }
      uint2 pk;
      pk.x = cvt_pk_bf16(hv[0], hv[1]);
      pk.y = cvt_pk_bf16(hv[2], hv[3]);
      *(uint2*)&z[1 - b][nt * 16 + ml][16 * w + 4 * q] = pk;
    }
  }

  // ---- drain: head(T-1), out(T-2), out(T-1) ----
  const int bl = (T - 1) & 1;
  __syncthreads();

  if (tid < 32) {
    float s = s_red[bl][tid][0] + s_red[bl][tid][1] +
              s_red[bl][tid][2] + s_red[bl][tid][3];
    out[(size_t)(T - 2) * N + n0 + tid] = sigmoidf_(s + h2b0);
  }
  #pragma unroll
  for (int nt = 0; nt < 2; nt++) {
    bf16x8_t B0 = *(const bf16x8_t*)&z[1 - bl][nt * 16 + ml][q * 8];
    bf16x8_t B1 = *(const bf16x8_t*)&z[1 - bl][nt * 16 + ml][32 + q * 8];
    f32x4_t ha = h1b4;
    ha = __builtin_amdgcn_mfma_f32_16x16x32_bf16(Ah[0], B0, ha, 0, 0, 0);
    ha = __builtin_amdgcn_mfma_f32_16x16x32_bf16(Ah[1], B1, ha, 0, 0, 0);
    float p = 0.0f;
    #pragma unroll
    for (int reg = 0; reg < 4; reg++)
      p += h2w_r[reg] * fmaxf(ha[reg], 0.0f);
    p += __shfl_xor(p, 16, 64);
    p += __shfl_xor(p, 32, 64);
    if (q == 0) s_red[1 - bl][nt * 16 + ml][w] = p;
  }
  __syncthreads();
  if (tid < 32) {
    float s = s_red[1 - bl][tid][0] + s_red[1 - bl][tid][1] +
              s_red[1 - bl][tid][2] + s_red[1 - bl][tid][3];
    out[(size_t)(T - 1) * N + n0 + tid] = sigmoidf_(s + h2b0);
  }
}

extern "C" void kernel_launch(void* const* d_in, const int* in_sizes, int n_in,
                              void* d_out, int out_size, void* d_ws, size_t ws_size,
                              hipStream_t stream) {
  const float* Xs   = (const float*)d_in[0];
  const float* Xd   = (const float*)d_in[1];
  const int*   erow = (const int*)d_in[2];
  const int*   ecol = (const int*)d_in[3];
  const float* evl  = (const float*)d_in[4];
  const float* g1W  = (const float*)d_in[5];
  const float* g1b  = (const float*)d_in[6];
  const float* g2W  = (const float*)d_in[7];
  const float* g2b  = (const float*)d_in[8];
  const float* Wih  = (const float*)d_in[9];
  const float* Whh  = (const float*)d_in[10];
  const float* bih  = (const float*)d_in[11];
  const float* bhh  = (const float*)d_in[12];
  const float* h1W  = (const float*)d_in[13];
  const float* h1b  = (const float*)d_in[14];
  const float* h2W  = (const float*)d_in[15];
  const float* h2b  = (const float*)d_in[16];

  const int N = in_sizes[0] / 32;
  const int E = in_sizes[2];
  const int T = in_sizes[1] / (N * 8);

  float* out  = (float*)d_out;
  char*  base = (char*)d_ws;
  float* buf0 = (float*)base;                     // N*32 f32 (also aliased as bf16)
  float* buf1 = buf0 + (size_t)N * 32;            // N*32 f32 (also aliased as bf16)
  int*   cnt    = (int*)(buf1 + (size_t)N * 32);  // N
  int*   startv = cnt + N;                        // N
  int*   cursor = startv + N;                     // N (tier B only)
  int*   bsum   = cursor + N;                     // 512 (tier B only)
  int*   bsumx  = bsum + 512;                     // 512 (tier B only)
  unsigned short* buf0h = (unsigned short*)buf0;  // bf16 view of buf0
  unsigned short* buf1h = (unsigned short*)buf1;  // bf16 view of buf1

  const int nBuckets = (N + BROWS - 1) >> BSHIFT;
  const int nbBin    = (E + EPB - 1) / EPB;

  int* bucketStart = bsumx + 512;                       // nBuckets+1
  int* bucketTotal = bucketStart + nBuckets + 1;        // nBuckets
  int* blockHist   = bucketTotal + nBuckets;            // nbBin*nBuckets
  int* blockCnt    = blockHist + (size_t)nbBin * nBuckets;  // nbBin*nBuckets
  char* pp = (char*)(blockCnt + (size_t)nbBin * nBuckets);
  pp = (char*)(((uintptr_t)pp + 15) & ~(uintptr_t)15);
  int2* pairs  = (int2*)pp;                             // E (both tiers)
  int2* binned = pairs + E;                             // E (tier A only)

  const size_t neededA = (size_t)((char*)(binned + E) - base);
  const size_t neededB = (size_t)((char*)(pairs + E) - base);

  const int linBlocks = (N + 7) / 8;
  const int eBlocks   = (E + 255) / 256;
  const int nb1       = (N + 255) / 256;

  const bool tierA = (ws_size >= neededA) && (nBuckets <= MAXBUCKETS) &&
                     (N <= (1 << 17));
  const bool tierB = !tierA && (ws_size >= neededB);

  if (tierA) {
    // lin32-g1 and hist_bin merged (independent subgraphs, one launch)
    lin_hist_k<<<linBlocks + nbBin, 256, 0, stream>>>(
        Xs, g1W, g1b, buf0h, N, linBlocks, erow, blockHist, blockCnt, E, nBuckets);

    colscan_k<<<nBuckets, 128, 0, stream>>>(blockHist, bucketTotal, nbBin, nBuckets);
    bucketstart_k<<<1, 1024, 0, stream>>>(bucketTotal, bucketStart, nBuckets);
    scatter_stage_k<<<nbBin, 256, 0, stream>>>(erow, ecol, evl, blockHist,
                                               blockCnt, bucketStart, binned,
                                               E, nBuckets);
    bucket_sort_k<<<nBuckets, 512, 0, stream>>>(bucketStart, binned, pairs,
                                                startv, cnt, N);

    // spmm1 fused relu+lin32-g2: read buf0h, write bf16 -> buf1h (NO alias)
    spmm_csr_bf16_k<true><<<(N + 3) / 4, 256, 0, stream>>>(
        startv, cnt, pairs, buf0h, buf1h, g2W, g2b, N);
    // spmm2: read buf1h, write f32 -> buf0
    spmm_csr_bf16_k<false><<<(N + 3) / 4, 256, 0, stream>>>(
        startv, cnt, pairs, buf1h, buf0, nullptr, nullptr, N);
  } else if (tierB) {
    // round-0 baseline CSR build (exact, random scatter)
    lin32_kernel<false, true><<<linBlocks, 256, 0, stream>>>(Xs, g1W, g1b, buf0h, N);

    hipMemsetAsync(cnt, 0, (size_t)N * sizeof(int), stream);
    hist_k<<<eBlocks, 256, 0, stream>>>(erow, cnt, E);
    scan1_k<<<nb1, 256, 0, stream>>>(cnt, startv, bsum, N);
    scan2_k<<<1, 512, 0, stream>>>(bsum, bsumx, nb1);
    scan3_k<<<nb1, 256, 0, stream>>>(startv, bsumx, cursor, N);
    scatter_k<<<eBlocks, 256, 0, stream>>>(erow, ecol, evl, cursor, pairs, E);

    spmm_csr_bf16_k<true><<<(N + 3) / 4, 256, 0, stream>>>(
        startv, cnt, pairs, buf0h, buf1h, g2W, g2b, N);
    spmm_csr_bf16_k<false><<<(N + 3) / 4, 256, 0, stream>>>(
        startv, cnt, pairs, buf1h, buf0, nullptr, nullptr, N);
  } else {
    // atomic fallback
    lin32_kernel<false, false><<<linBlocks, 256, 0, stream>>>(Xs, g1W, g1b, buf1, N);
    const int spmmBlocks = (int)(((long)E * 8 + 255) / 256);
    hipMemsetAsync(buf0, 0, (size_t)N * 32 * sizeof(float), stream);
    spmm_kernel<<<spmmBlocks, 256, 0, stream>>>(erow, ecol, evl, buf1, buf0, E);
    lin32_kernel<true, false><<<linBlocks, 256, 0, stream>>>(buf0, g2W, g2b, buf1, N);
    hipMemsetAsync(buf0, 0, (size_t)N * 32 * sizeof(float), stream);
    spmm_kernel<<<spmmBlocks, 256, 0, stream>>>(erow, ecol, evl, buf1, buf0, E);
  }

  // fused MFMA GRU + head (acc2 = buf0, f32)
  gru_head_mfma<<<N / NB, 256, 0, stream>>>(buf0, Xd, Wih, Whh, bih, bhh,
                                            h1W, h1b, h2W, h2b, out, N, T);
}